// Round 1
// baseline (2123.378 us; speedup 1.0000x reference)
//
#include <hip/hip_runtime.h>

// ---------------------------------------------------------------------------
// TreeConv GNN: agg = scatter_add(h[src] -> dst) + h ; MLP per node.
// Baseline: atomic scatter + fused per-node MLPs with LDS-staged weights.
// ---------------------------------------------------------------------------

template <int DIM4>  // row size in float4s (8 for dim=32, 16 for dim=64)
__global__ __launch_bounds__(256) void scatter_add_kernel(
    const float* __restrict__ h, const int* __restrict__ src,
    const int* __restrict__ dst, float* __restrict__ agg, int n_edges) {
  constexpr int SH = (DIM4 == 8) ? 3 : 4;
  constexpr int DIM = DIM4 * 4;
  const long total = (long)n_edges * DIM4;
  for (long i = (long)blockIdx.x * blockDim.x + threadIdx.x; i < total;
       i += (long)gridDim.x * blockDim.x) {
    const int e = (int)(i >> SH);
    const int q = (int)(i & (DIM4 - 1));
    const int s = src[e];
    const int d = dst[e];
    const float4 v =
        *reinterpret_cast<const float4*>(h + (long)s * DIM + q * 4);
    float* o = agg + (long)d * DIM + q * 4;
    atomicAdd(o + 0, v.x);
    atomicAdd(o + 1, v.y);
    atomicAdd(o + 2, v.z);
    atomicAdd(o + 3, v.w);
  }
}

// Layer 0: h0 = relu(agg0 @ w1 + b1) @ w2 + b2   (32 -> 64 -> 64)
__global__ __launch_bounds__(256) void mlp0_kernel(
    const float* __restrict__ agg, const float* __restrict__ w1,
    const float* __restrict__ b1, const float* __restrict__ w2,
    const float* __restrict__ b2, float* __restrict__ h0, int n_nodes) {
  __shared__ float w1s[32 * 64];  // transposed: w1s[j*32+k]
  __shared__ float w2s[64 * 64];  // row-major:  w2s[j*64+j2]
  __shared__ float b1s[64], b2s[64];
  for (int i = threadIdx.x; i < 32 * 64; i += 256) {
    int k = i >> 6, j = i & 63;
    w1s[j * 32 + k] = w1[i];
  }
  for (int i = threadIdx.x; i < 64 * 64; i += 256) w2s[i] = w2[i];
  if (threadIdx.x < 64) {
    b1s[threadIdx.x] = b1[threadIdx.x];
    b2s[threadIdx.x] = b2[threadIdx.x];
  }
  __syncthreads();

  const int node = blockIdx.x * 256 + threadIdx.x;
  if (node >= n_nodes) return;

  float a[32];
  const float4* ap = reinterpret_cast<const float4*>(agg + (long)node * 32);
#pragma unroll
  for (int q = 0; q < 8; q++) {
    float4 v = ap[q];
    a[q * 4 + 0] = v.x; a[q * 4 + 1] = v.y;
    a[q * 4 + 2] = v.z; a[q * 4 + 3] = v.w;
  }
  float h[64];
#pragma unroll
  for (int j2 = 0; j2 < 64; j2++) h[j2] = b2s[j2];

  for (int j = 0; j < 64; j++) {
    const float* wc = &w1s[j * 32];
    float z0 = 0.f, z1 = 0.f, z2 = 0.f, z3 = 0.f;
#pragma unroll
    for (int k = 0; k < 32; k += 4) {
      z0 = fmaf(a[k + 0], wc[k + 0], z0);
      z1 = fmaf(a[k + 1], wc[k + 1], z1);
      z2 = fmaf(a[k + 2], wc[k + 2], z2);
      z3 = fmaf(a[k + 3], wc[k + 3], z3);
    }
    const float z = fmaxf(z0 + z1 + z2 + z3 + b1s[j], 0.0f);
    const float* wr = &w2s[j * 64];
#pragma unroll
    for (int j2 = 0; j2 < 64; j2++) h[j2] = fmaf(z, wr[j2], h[j2]);
  }

  float4* hp = reinterpret_cast<float4*>(h0 + (long)node * 64);
#pragma unroll
  for (int q = 0; q < 16; q++)
    hp[q] = make_float4(h[q * 4], h[q * 4 + 1], h[q * 4 + 2], h[q * 4 + 3]);
}

// Layer 1 + classifier fused:
// h1 = relu(agg1 @ w1 + b1) @ w2 + b2 ; out = relu(h1 @ cw1 + cb1) @ cw2 + cb2
__global__ __launch_bounds__(256) void mlp1_cls_kernel(
    const float* __restrict__ agg, const float* __restrict__ w1,
    const float* __restrict__ b1, const float* __restrict__ w2,
    const float* __restrict__ b2, const float* __restrict__ cw1,
    const float* __restrict__ cb1, const float* __restrict__ cw2,
    const float* __restrict__ cb2, float* __restrict__ out, int n_nodes) {
  __shared__ float w1s[64 * 64];   // transposed
  __shared__ float w2s[64 * 64];   // row-major
  __shared__ float cw1s[64 * 64];  // transposed
  __shared__ float cw2s[64 * 16];  // row-major
  __shared__ float b1s[64], b2s[64], cb1s[64], cb2s[16];
  for (int i = threadIdx.x; i < 4096; i += 256) {
    int k = i >> 6, j = i & 63;
    w1s[j * 64 + k] = w1[i];
    cw1s[j * 64 + k] = cw1[i];
    w2s[i] = w2[i];
  }
  for (int i = threadIdx.x; i < 1024; i += 256) cw2s[i] = cw2[i];
  if (threadIdx.x < 64) {
    b1s[threadIdx.x] = b1[threadIdx.x];
    b2s[threadIdx.x] = b2[threadIdx.x];
    cb1s[threadIdx.x] = cb1[threadIdx.x];
  }
  if (threadIdx.x < 16) cb2s[threadIdx.x] = cb2[threadIdx.x];
  __syncthreads();

  const int node = blockIdx.x * 256 + threadIdx.x;
  if (node >= n_nodes) return;

  float a[64];
  const float4* ap = reinterpret_cast<const float4*>(agg + (long)node * 64);
#pragma unroll
  for (int q = 0; q < 16; q++) {
    float4 v = ap[q];
    a[q * 4 + 0] = v.x; a[q * 4 + 1] = v.y;
    a[q * 4 + 2] = v.z; a[q * 4 + 3] = v.w;
  }

  float h[64];
#pragma unroll
  for (int j2 = 0; j2 < 64; j2++) h[j2] = b2s[j2];

  for (int j = 0; j < 64; j++) {
    const float* wc = &w1s[j * 64];
    float z0 = 0.f, z1 = 0.f, z2 = 0.f, z3 = 0.f;
#pragma unroll
    for (int k = 0; k < 64; k += 4) {
      z0 = fmaf(a[k + 0], wc[k + 0], z0);
      z1 = fmaf(a[k + 1], wc[k + 1], z1);
      z2 = fmaf(a[k + 2], wc[k + 2], z2);
      z3 = fmaf(a[k + 3], wc[k + 3], z3);
    }
    const float z = fmaxf(z0 + z1 + z2 + z3 + b1s[j], 0.0f);
    const float* wr = &w2s[j * 64];
#pragma unroll
    for (int j2 = 0; j2 < 64; j2++) h[j2] = fmaf(z, wr[j2], h[j2]);
  }

  float o[16];
#pragma unroll
  for (int t = 0; t < 16; t++) o[t] = cb2s[t];

  for (int j = 0; j < 64; j++) {
    const float* wc = &cw1s[j * 64];
    float z0 = 0.f, z1 = 0.f, z2 = 0.f, z3 = 0.f;
#pragma unroll
    for (int k = 0; k < 64; k += 4) {
      z0 = fmaf(h[k + 0], wc[k + 0], z0);
      z1 = fmaf(h[k + 1], wc[k + 1], z1);
      z2 = fmaf(h[k + 2], wc[k + 2], z2);
      z3 = fmaf(h[k + 3], wc[k + 3], z3);
    }
    const float z = fmaxf(z0 + z1 + z2 + z3 + cb1s[j], 0.0f);
    const float* wr = &cw2s[j * 16];
#pragma unroll
    for (int t = 0; t < 16; t++) o[t] = fmaf(z, wr[t], o[t]);
  }

  float4* op = reinterpret_cast<float4*>(out + (long)node * 16);
#pragma unroll
  for (int q = 0; q < 4; q++)
    op[q] = make_float4(o[q * 4], o[q * 4 + 1], o[q * 4 + 2], o[q * 4 + 3]);
}

extern "C" void kernel_launch(void* const* d_in, const int* in_sizes, int n_in,
                              void* d_out, int out_size, void* d_ws,
                              size_t ws_size, hipStream_t stream) {
  const float* x = (const float*)d_in[0];
  const int* ei = (const int*)d_in[1];
  const float* w1_0 = (const float*)d_in[2];
  const float* b1_0 = (const float*)d_in[3];
  const float* w2_0 = (const float*)d_in[4];
  const float* b2_0 = (const float*)d_in[5];
  const float* w1_1 = (const float*)d_in[6];
  const float* b1_1 = (const float*)d_in[7];
  const float* w2_1 = (const float*)d_in[8];
  const float* b2_1 = (const float*)d_in[9];
  const float* cw1 = (const float*)d_in[10];
  const float* cb1 = (const float*)d_in[11];
  const float* cw2 = (const float*)d_in[12];
  const float* cb2 = (const float*)d_in[13];

  const int n_nodes = in_sizes[0] / 32;
  const int n_edges = in_sizes[1] / 2;
  const int* src = ei;
  const int* dst = ei + n_edges;

  float* agg0 = (float*)d_ws;                  // n_nodes*32
  float* h0 = agg0 + (size_t)n_nodes * 32;     // n_nodes*64
  float* agg1 = h0 + (size_t)n_nodes * 64;     // n_nodes*64

  // agg0 = x  (self-loop term), then scatter-add x[src] rows into agg0[dst]
  hipMemcpyAsync(agg0, x, (size_t)n_nodes * 32 * sizeof(float),
                 hipMemcpyDeviceToDevice, stream);
  {
    long total = (long)n_edges * 8;
    int blocks = (int)((total + 255) / 256);
    if (blocks > 8192) blocks = 8192;
    scatter_add_kernel<8><<<blocks, 256, 0, stream>>>(x, src, dst, agg0,
                                                      n_edges);
  }

  const int nb = (n_nodes + 255) / 256;
  mlp0_kernel<<<nb, 256, 0, stream>>>(agg0, w1_0, b1_0, w2_0, b2_0, h0,
                                      n_nodes);

  // agg1 = h0, then scatter-add h0[src] rows into agg1[dst]
  hipMemcpyAsync(agg1, h0, (size_t)n_nodes * 64 * sizeof(float),
                 hipMemcpyDeviceToDevice, stream);
  {
    long total = (long)n_edges * 16;
    int blocks = (int)((total + 255) / 256);
    if (blocks > 8192) blocks = 8192;
    scatter_add_kernel<16><<<blocks, 256, 0, stream>>>(h0, src, dst, agg1,
                                                       n_edges);
  }

  mlp1_cls_kernel<<<nb, 256, 0, stream>>>(agg1, w1_1, b1_1, w2_1, b2_1, cw1,
                                          cb1, cw2, cb2, (float*)d_out,
                                          n_nodes);
}

// Round 2
// 511.489 us; speedup vs baseline: 4.1514x; 4.1514x over previous
//
#include <hip/hip_runtime.h>

// ---------------------------------------------------------------------------
// TreeConv GNN. R1: replace float atomic scatter with per-call CSR build
// (counting sort by dst) + register-accumulating gather. CSR is reused for
// both conv layers. MLPs unchanged (LDS-staged weights, thread-per-node).
// ---------------------------------------------------------------------------

__global__ __launch_bounds__(256) void count_deg_kernel(
    const int* __restrict__ dst, int* __restrict__ deg, int n_edges) {
  for (int e = blockIdx.x * 256 + threadIdx.x; e < n_edges;
       e += gridDim.x * 256)
    atomicAdd(&deg[dst[e]], 1);
}

// Single-block exclusive scan of deg[0..n) -> off[0..n]
__global__ __launch_bounds__(1024) void scan_kernel(
    const int* __restrict__ deg, int* __restrict__ off, int n) {
  __shared__ int wsum[16];
  __shared__ int carry_s;
  if (threadIdx.x == 0) carry_s = 0;
  __syncthreads();
  const int lane = threadIdx.x & 63;
  const int wid = threadIdx.x >> 6;
  for (int base = 0; base < n; base += 1024) {
    const int i = base + threadIdx.x;
    const int v = (i < n) ? deg[i] : 0;
    int x = v;  // inclusive wave scan
#pragma unroll
    for (int s = 1; s < 64; s <<= 1) {
      int t = __shfl_up(x, s, 64);
      if (lane >= s) x += t;
    }
    if (lane == 63) wsum[wid] = x;
    __syncthreads();
    if (wid == 0 && lane < 16) {
      int y = wsum[lane];
#pragma unroll
      for (int s = 1; s < 16; s <<= 1) {
        int t = __shfl_up(y, s, 64);
        if (lane >= s) y += t;
      }
      wsum[lane] = y;
    }
    __syncthreads();
    const int wbase = (wid == 0) ? 0 : wsum[wid - 1];
    const int incl = carry_s + wbase + x;
    if (i < n) off[i] = incl - v;  // exclusive
    __syncthreads();
    if (threadIdx.x == 1023) carry_s += wsum[15];
    __syncthreads();
  }
  if (threadIdx.x == 0) off[n] = carry_s;
}

__global__ __launch_bounds__(256) void init_cursor_kernel(
    const int* __restrict__ off, int* __restrict__ cur, int n) {
  for (int i = blockIdx.x * 256 + threadIdx.x; i < n; i += gridDim.x * 256)
    cur[i] = off[i];
}

__global__ __launch_bounds__(256) void fill_csr_kernel(
    const int* __restrict__ src, const int* __restrict__ dst,
    int* __restrict__ cur, int* __restrict__ csr, int n_edges) {
  for (int e = blockIdx.x * 256 + threadIdx.x; e < n_edges;
       e += gridDim.x * 256) {
    const int p = atomicAdd(&cur[dst[e]], 1);
    csr[p] = src[e];
  }
}

// agg[node] = h[node] + sum_{e in CSR[node]} h[csr[e]]
// L lanes per node, each lane owns one float4 of the row (D = 4*L).
template <int L>
__global__ __launch_bounds__(256) void gather_kernel(
    const float* __restrict__ h, const int* __restrict__ off,
    const int* __restrict__ csr, float* __restrict__ agg, int n_nodes) {
  const int gid = (blockIdx.x * 256 + threadIdx.x) / L;
  const int lane = threadIdx.x & (L - 1);
  if (gid >= n_nodes) return;
  constexpr int D = L * 4;
  float4 acc =
      *reinterpret_cast<const float4*>(h + (size_t)gid * D + lane * 4);
  const int e0 = off[gid], e1 = off[gid + 1];
  for (int e = e0; e < e1; ++e) {
    const int s = csr[e];
    const float4 v =
        *reinterpret_cast<const float4*>(h + (size_t)s * D + lane * 4);
    acc.x += v.x; acc.y += v.y; acc.z += v.z; acc.w += v.w;
  }
  *reinterpret_cast<float4*>(agg + (size_t)gid * D + lane * 4) = acc;
}

// Layer 0: h0 = relu(agg0 @ w1 + b1) @ w2 + b2   (32 -> 64 -> 64)
__global__ __launch_bounds__(256) void mlp0_kernel(
    const float* __restrict__ agg, const float* __restrict__ w1,
    const float* __restrict__ b1, const float* __restrict__ w2,
    const float* __restrict__ b2, float* __restrict__ h0, int n_nodes) {
  __shared__ float w1s[32 * 64];  // transposed: w1s[j*32+k]
  __shared__ float w2s[64 * 64];  // row-major
  __shared__ float b1s[64], b2s[64];
  for (int i = threadIdx.x; i < 32 * 64; i += 256) {
    int k = i >> 6, j = i & 63;
    w1s[j * 32 + k] = w1[i];
  }
  for (int i = threadIdx.x; i < 64 * 64; i += 256) w2s[i] = w2[i];
  if (threadIdx.x < 64) {
    b1s[threadIdx.x] = b1[threadIdx.x];
    b2s[threadIdx.x] = b2[threadIdx.x];
  }
  __syncthreads();

  const int node = blockIdx.x * 256 + threadIdx.x;
  if (node >= n_nodes) return;

  float a[32];
  const float4* ap = reinterpret_cast<const float4*>(agg + (long)node * 32);
#pragma unroll
  for (int q = 0; q < 8; q++) {
    float4 v = ap[q];
    a[q * 4 + 0] = v.x; a[q * 4 + 1] = v.y;
    a[q * 4 + 2] = v.z; a[q * 4 + 3] = v.w;
  }
  float h[64];
#pragma unroll
  for (int j2 = 0; j2 < 64; j2++) h[j2] = b2s[j2];

  for (int j = 0; j < 64; j++) {
    const float* wc = &w1s[j * 32];
    float z0 = 0.f, z1 = 0.f, z2 = 0.f, z3 = 0.f;
#pragma unroll
    for (int k = 0; k < 32; k += 4) {
      z0 = fmaf(a[k + 0], wc[k + 0], z0);
      z1 = fmaf(a[k + 1], wc[k + 1], z1);
      z2 = fmaf(a[k + 2], wc[k + 2], z2);
      z3 = fmaf(a[k + 3], wc[k + 3], z3);
    }
    const float z = fmaxf(z0 + z1 + z2 + z3 + b1s[j], 0.0f);
    const float* wr = &w2s[j * 64];
#pragma unroll
    for (int j2 = 0; j2 < 64; j2++) h[j2] = fmaf(z, wr[j2], h[j2]);
  }

  float4* hp = reinterpret_cast<float4*>(h0 + (long)node * 64);
#pragma unroll
  for (int q = 0; q < 16; q++)
    hp[q] = make_float4(h[q * 4], h[q * 4 + 1], h[q * 4 + 2], h[q * 4 + 3]);
}

// Layer 1 + classifier fused.
__global__ __launch_bounds__(256) void mlp1_cls_kernel(
    const float* __restrict__ agg, const float* __restrict__ w1,
    const float* __restrict__ b1, const float* __restrict__ w2,
    const float* __restrict__ b2, const float* __restrict__ cw1,
    const float* __restrict__ cb1, const float* __restrict__ cw2,
    const float* __restrict__ cb2, float* __restrict__ out, int n_nodes) {
  __shared__ float w1s[64 * 64];   // transposed
  __shared__ float w2s[64 * 64];   // row-major
  __shared__ float cw1s[64 * 64];  // transposed
  __shared__ float cw2s[64 * 16];  // row-major
  __shared__ float b1s[64], b2s[64], cb1s[64], cb2s[16];
  for (int i = threadIdx.x; i < 4096; i += 256) {
    int k = i >> 6, j = i & 63;
    w1s[j * 64 + k] = w1[i];
    cw1s[j * 64 + k] = cw1[i];
    w2s[i] = w2[i];
  }
  for (int i = threadIdx.x; i < 1024; i += 256) cw2s[i] = cw2[i];
  if (threadIdx.x < 64) {
    b1s[threadIdx.x] = b1[threadIdx.x];
    b2s[threadIdx.x] = b2[threadIdx.x];
    cb1s[threadIdx.x] = cb1[threadIdx.x];
  }
  if (threadIdx.x < 16) cb2s[threadIdx.x] = cb2[threadIdx.x];
  __syncthreads();

  const int node = blockIdx.x * 256 + threadIdx.x;
  if (node >= n_nodes) return;

  float a[64];
  const float4* ap = reinterpret_cast<const float4*>(agg + (long)node * 64);
#pragma unroll
  for (int q = 0; q < 16; q++) {
    float4 v = ap[q];
    a[q * 4 + 0] = v.x; a[q * 4 + 1] = v.y;
    a[q * 4 + 2] = v.z; a[q * 4 + 3] = v.w;
  }

  float h[64];
#pragma unroll
  for (int j2 = 0; j2 < 64; j2++) h[j2] = b2s[j2];

  for (int j = 0; j < 64; j++) {
    const float* wc = &w1s[j * 64];
    float z0 = 0.f, z1 = 0.f, z2 = 0.f, z3 = 0.f;
#pragma unroll
    for (int k = 0; k < 64; k += 4) {
      z0 = fmaf(a[k + 0], wc[k + 0], z0);
      z1 = fmaf(a[k + 1], wc[k + 1], z1);
      z2 = fmaf(a[k + 2], wc[k + 2], z2);
      z3 = fmaf(a[k + 3], wc[k + 3], z3);
    }
    const float z = fmaxf(z0 + z1 + z2 + z3 + b1s[j], 0.0f);
    const float* wr = &w2s[j * 64];
#pragma unroll
    for (int j2 = 0; j2 < 64; j2++) h[j2] = fmaf(z, wr[j2], h[j2]);
  }

  float o[16];
#pragma unroll
  for (int t = 0; t < 16; t++) o[t] = cb2s[t];

  for (int j = 0; j < 64; j++) {
    const float* wc = &cw1s[j * 64];
    float z0 = 0.f, z1 = 0.f, z2 = 0.f, z3 = 0.f;
#pragma unroll
    for (int k = 0; k < 64; k += 4) {
      z0 = fmaf(h[k + 0], wc[k + 0], z0);
      z1 = fmaf(h[k + 1], wc[k + 1], z1);
      z2 = fmaf(h[k + 2], wc[k + 2], z2);
      z3 = fmaf(h[k + 3], wc[k + 3], z3);
    }
    const float z = fmaxf(z0 + z1 + z2 + z3 + cb1s[j], 0.0f);
    const float* wr = &cw2s[j * 16];
#pragma unroll
    for (int t = 0; t < 16; t++) o[t] = fmaf(z, wr[t], o[t]);
  }

  float4* op = reinterpret_cast<float4*>(out + (long)node * 16);
#pragma unroll
  for (int q = 0; q < 4; q++)
    op[q] = make_float4(o[q * 4], o[q * 4 + 1], o[q * 4 + 2], o[q * 4 + 3]);
}

extern "C" void kernel_launch(void* const* d_in, const int* in_sizes, int n_in,
                              void* d_out, int out_size, void* d_ws,
                              size_t ws_size, hipStream_t stream) {
  const float* x = (const float*)d_in[0];
  const int* ei = (const int*)d_in[1];
  const float* w1_0 = (const float*)d_in[2];
  const float* b1_0 = (const float*)d_in[3];
  const float* w2_0 = (const float*)d_in[4];
  const float* b2_0 = (const float*)d_in[5];
  const float* w1_1 = (const float*)d_in[6];
  const float* b1_1 = (const float*)d_in[7];
  const float* w2_1 = (const float*)d_in[8];
  const float* b2_1 = (const float*)d_in[9];
  const float* cw1 = (const float*)d_in[10];
  const float* cb1 = (const float*)d_in[11];
  const float* cw2 = (const float*)d_in[12];
  const float* cb2 = (const float*)d_in[13];

  const int n = in_sizes[0] / 32;       // nodes
  const int ne = in_sizes[1] / 2;       // edges
  const int* src = ei;
  const int* dst = ei + ne;

  // Workspace layout
  float* agg0 = (float*)d_ws;                   // n*32
  float* h0 = agg0 + (size_t)n * 32;            // n*64
  float* agg1 = h0 + (size_t)n * 64;            // n*64
  int* deg = (int*)(agg1 + (size_t)n * 64);     // n
  int* off = deg + n;                           // n+1
  int* cur = off + n + 1;                       // n
  int* csr = cur + n;                           // ne

  // --- CSR build (counting sort by dst), reused by both layers ---
  hipMemsetAsync(deg, 0, (size_t)n * sizeof(int), stream);
  {
    int blocks = (ne + 255) / 256;
    if (blocks > 2048) blocks = 2048;
    count_deg_kernel<<<blocks, 256, 0, stream>>>(dst, deg, ne);
  }
  scan_kernel<<<1, 1024, 0, stream>>>(deg, off, n);
  init_cursor_kernel<<<(n + 255) / 256, 256, 0, stream>>>(off, cur, n);
  {
    int blocks = (ne + 255) / 256;
    if (blocks > 2048) blocks = 2048;
    fill_csr_kernel<<<blocks, 256, 0, stream>>>(src, dst, cur, csr, ne);
  }

  // --- Layer 0 ---
  gather_kernel<8><<<((size_t)n * 8 + 255) / 256, 256, 0, stream>>>(
      x, off, csr, agg0, n);
  const int nb = (n + 255) / 256;
  mlp0_kernel<<<nb, 256, 0, stream>>>(agg0, w1_0, b1_0, w2_0, b2_0, h0, n);

  // --- Layer 1 + classifier ---
  gather_kernel<16><<<((size_t)n * 16 + 255) / 256, 256, 0, stream>>>(
      h0, off, csr, agg1, n);
  mlp1_cls_kernel<<<nb, 256, 0, stream>>>(agg1, w1_1, b1_1, w2_1, b2_1, cw1,
                                          cb1, cw2, cb2, (float*)d_out, n);
}

// Round 3
// 394.791 us; speedup vs baseline: 5.3785x; 1.2956x over previous
//
#include <hip/hip_runtime.h>

// ---------------------------------------------------------------------------
// TreeConv GNN. R2: two-level counting sort for CSR build.
//   count_deg -> parallel scan (3 kernels) -> bucket partition (int2, padded
//   bucket cursors) -> per-bucket fill (LDS cursors, L2-local csr writes)
// Gather + MLP kernels unchanged from R1.
// ---------------------------------------------------------------------------

#define NODES_PER_BUCKET 128  // bucket id = dst >> 7

__global__ __launch_bounds__(256) void count_deg_kernel(
    const int* __restrict__ dst, int* __restrict__ deg, int n_edges) {
  for (int e = blockIdx.x * 256 + threadIdx.x; e < n_edges;
       e += gridDim.x * 256)
    atomicAdd(&deg[dst[e]], 1);
}

// scan1: per-1024-chunk exclusive scan + chunk totals
__global__ __launch_bounds__(1024) void scan1_kernel(
    const int* __restrict__ deg, int* __restrict__ off,
    int* __restrict__ partial, int n) {
  __shared__ int wsum[16];
  const int lane = threadIdx.x & 63;
  const int wid = threadIdx.x >> 6;
  const int i = blockIdx.x * 1024 + threadIdx.x;
  const int v = (i < n) ? deg[i] : 0;
  int x = v;
#pragma unroll
  for (int s = 1; s < 64; s <<= 1) {
    int t = __shfl_up(x, s, 64);
    if (lane >= s) x += t;
  }
  if (lane == 63) wsum[wid] = x;
  __syncthreads();
  if (wid == 0 && lane < 16) {
    int y = wsum[lane];
#pragma unroll
    for (int s = 1; s < 16; s <<= 1) {
      int t = __shfl_up(y, s, 64);
      if (lane >= s) y += t;
    }
    wsum[lane] = y;
  }
  __syncthreads();
  const int wbase = (wid == 0) ? 0 : wsum[wid - 1];
  if (i < n) off[i] = wbase + x - v;  // chunk-local exclusive
  if (threadIdx.x == 1023) partial[blockIdx.x] = wsum[15];
}

// scan2: single block, exclusive scan of chunk totals in place (np <= 1024)
__global__ __launch_bounds__(1024) void scan2_kernel(int* __restrict__ partial,
                                                     int np) {
  __shared__ int wsum[16];
  const int lane = threadIdx.x & 63;
  const int wid = threadIdx.x >> 6;
  const int i = threadIdx.x;
  const int v = (i < np) ? partial[i] : 0;
  int x = v;
#pragma unroll
  for (int s = 1; s < 64; s <<= 1) {
    int t = __shfl_up(x, s, 64);
    if (lane >= s) x += t;
  }
  if (lane == 63) wsum[wid] = x;
  __syncthreads();
  if (wid == 0 && lane < 16) {
    int y = wsum[lane];
#pragma unroll
    for (int s = 1; s < 16; s <<= 1) {
      int t = __shfl_up(y, s, 64);
      if (lane >= s) y += t;
    }
    wsum[lane] = y;
  }
  __syncthreads();
  const int wbase = (wid == 0) ? 0 : wsum[wid - 1];
  if (i < np) partial[i] = wbase + x - v;  // exclusive
}

// scan3: add chunk bases; emit padded bucket cursors; write off[n]
__global__ __launch_bounds__(256) void scan3_kernel(
    int* __restrict__ off, const int* __restrict__ base,
    int* __restrict__ bcur, int n, int ne) {
  const int i = blockIdx.x * 256 + threadIdx.x;
  if (i == 0) off[n] = ne;
  if (i < n) {
    const int o = off[i] + base[i >> 10];
    off[i] = o;
    if ((i & (NODES_PER_BUCKET - 1)) == 0)
      bcur[(i >> 7) * 16] = o;  // 64B-padded cursor per bucket
  }
}

__global__ __launch_bounds__(256) void partition_kernel(
    const int* __restrict__ src, const int* __restrict__ dst,
    int* __restrict__ bcur, int2* __restrict__ sorted, int n_edges) {
  for (int e = blockIdx.x * 256 + threadIdx.x; e < n_edges;
       e += gridDim.x * 256) {
    const int s = src[e];
    const int d = dst[e];
    const int p = atomicAdd(&bcur[(d >> 7) * 16], 1);
    sorted[p] = make_int2(s, d);
  }
}

// One block per bucket: per-node cursors in LDS, csr writes stay in an
// ~8KB L2-resident region.
__global__ __launch_bounds__(256) void fill_bucket_kernel(
    const int2* __restrict__ sorted, const int* __restrict__ off,
    int* __restrict__ csr, int n) {
  __shared__ int lcur[NODES_PER_BUCKET];
  const int base_node = blockIdx.x << 7;
  const int end_node = min(base_node + NODES_PER_BUCKET, n);
  const int nn = end_node - base_node;
  if (threadIdx.x < nn) lcur[threadIdx.x] = off[base_node + threadIdx.x];
  __syncthreads();
  const int e0 = off[base_node];
  const int e1 = off[end_node];
  for (int e = e0 + threadIdx.x; e < e1; e += 256) {
    const int2 ed = sorted[e];
    const int p = atomicAdd(&lcur[ed.y - base_node], 1);
    csr[p] = ed.x;
  }
}

// agg[node] = h[node] + sum_{e in CSR[node]} h[csr[e]]
template <int L>
__global__ __launch_bounds__(256) void gather_kernel(
    const float* __restrict__ h, const int* __restrict__ off,
    const int* __restrict__ csr, float* __restrict__ agg, int n_nodes) {
  const int gid = (blockIdx.x * 256 + threadIdx.x) / L;
  const int lane = threadIdx.x & (L - 1);
  if (gid >= n_nodes) return;
  constexpr int D = L * 4;
  float4 acc =
      *reinterpret_cast<const float4*>(h + (size_t)gid * D + lane * 4);
  const int e0 = off[gid], e1 = off[gid + 1];
  for (int e = e0; e < e1; ++e) {
    const int s = csr[e];
    const float4 v =
        *reinterpret_cast<const float4*>(h + (size_t)s * D + lane * 4);
    acc.x += v.x; acc.y += v.y; acc.z += v.z; acc.w += v.w;
  }
  *reinterpret_cast<float4*>(agg + (size_t)gid * D + lane * 4) = acc;
}

// Layer 0: h0 = relu(agg0 @ w1 + b1) @ w2 + b2   (32 -> 64 -> 64)
__global__ __launch_bounds__(256) void mlp0_kernel(
    const float* __restrict__ agg, const float* __restrict__ w1,
    const float* __restrict__ b1, const float* __restrict__ w2,
    const float* __restrict__ b2, float* __restrict__ h0, int n_nodes) {
  __shared__ float w1s[32 * 64];  // transposed
  __shared__ float w2s[64 * 64];  // row-major
  __shared__ float b1s[64], b2s[64];
  for (int i = threadIdx.x; i < 32 * 64; i += 256) {
    int k = i >> 6, j = i & 63;
    w1s[j * 32 + k] = w1[i];
  }
  for (int i = threadIdx.x; i < 64 * 64; i += 256) w2s[i] = w2[i];
  if (threadIdx.x < 64) {
    b1s[threadIdx.x] = b1[threadIdx.x];
    b2s[threadIdx.x] = b2[threadIdx.x];
  }
  __syncthreads();

  const int node = blockIdx.x * 256 + threadIdx.x;
  if (node >= n_nodes) return;

  float a[32];
  const float4* ap = reinterpret_cast<const float4*>(agg + (long)node * 32);
#pragma unroll
  for (int q = 0; q < 8; q++) {
    float4 v = ap[q];
    a[q * 4 + 0] = v.x; a[q * 4 + 1] = v.y;
    a[q * 4 + 2] = v.z; a[q * 4 + 3] = v.w;
  }
  float h[64];
#pragma unroll
  for (int j2 = 0; j2 < 64; j2++) h[j2] = b2s[j2];

  for (int j = 0; j < 64; j++) {
    const float* wc = &w1s[j * 32];
    float z0 = 0.f, z1 = 0.f, z2 = 0.f, z3 = 0.f;
#pragma unroll
    for (int k = 0; k < 32; k += 4) {
      z0 = fmaf(a[k + 0], wc[k + 0], z0);
      z1 = fmaf(a[k + 1], wc[k + 1], z1);
      z2 = fmaf(a[k + 2], wc[k + 2], z2);
      z3 = fmaf(a[k + 3], wc[k + 3], z3);
    }
    const float z = fmaxf(z0 + z1 + z2 + z3 + b1s[j], 0.0f);
    const float* wr = &w2s[j * 64];
#pragma unroll
    for (int j2 = 0; j2 < 64; j2++) h[j2] = fmaf(z, wr[j2], h[j2]);
  }

  float4* hp = reinterpret_cast<float4*>(h0 + (long)node * 64);
#pragma unroll
  for (int q = 0; q < 16; q++)
    hp[q] = make_float4(h[q * 4], h[q * 4 + 1], h[q * 4 + 2], h[q * 4 + 3]);
}

// Layer 1 + classifier fused.
__global__ __launch_bounds__(256) void mlp1_cls_kernel(
    const float* __restrict__ agg, const float* __restrict__ w1,
    const float* __restrict__ b1, const float* __restrict__ w2,
    const float* __restrict__ b2, const float* __restrict__ cw1,
    const float* __restrict__ cb1, const float* __restrict__ cw2,
    const float* __restrict__ cb2, float* __restrict__ out, int n_nodes) {
  __shared__ float w1s[64 * 64];   // transposed
  __shared__ float w2s[64 * 64];   // row-major
  __shared__ float cw1s[64 * 64];  // transposed
  __shared__ float cw2s[64 * 16];  // row-major
  __shared__ float b1s[64], b2s[64], cb1s[64], cb2s[16];
  for (int i = threadIdx.x; i < 4096; i += 256) {
    int k = i >> 6, j = i & 63;
    w1s[j * 64 + k] = w1[i];
    cw1s[j * 64 + k] = cw1[i];
    w2s[i] = w2[i];
  }
  for (int i = threadIdx.x; i < 1024; i += 256) cw2s[i] = cw2[i];
  if (threadIdx.x < 64) {
    b1s[threadIdx.x] = b1[threadIdx.x];
    b2s[threadIdx.x] = b2[threadIdx.x];
    cb1s[threadIdx.x] = cb1[threadIdx.x];
  }
  if (threadIdx.x < 16) cb2s[threadIdx.x] = cb2[threadIdx.x];
  __syncthreads();

  const int node = blockIdx.x * 256 + threadIdx.x;
  if (node >= n_nodes) return;

  float a[64];
  const float4* ap = reinterpret_cast<const float4*>(agg + (long)node * 64);
#pragma unroll
  for (int q = 0; q < 16; q++) {
    float4 v = ap[q];
    a[q * 4 + 0] = v.x; a[q * 4 + 1] = v.y;
    a[q * 4 + 2] = v.z; a[q * 4 + 3] = v.w;
  }

  float h[64];
#pragma unroll
  for (int j2 = 0; j2 < 64; j2++) h[j2] = b2s[j2];

  for (int j = 0; j < 64; j++) {
    const float* wc = &w1s[j * 64];
    float z0 = 0.f, z1 = 0.f, z2 = 0.f, z3 = 0.f;
#pragma unroll
    for (int k = 0; k < 64; k += 4) {
      z0 = fmaf(a[k + 0], wc[k + 0], z0);
      z1 = fmaf(a[k + 1], wc[k + 1], z1);
      z2 = fmaf(a[k + 2], wc[k + 2], z2);
      z3 = fmaf(a[k + 3], wc[k + 3], z3);
    }
    const float z = fmaxf(z0 + z1 + z2 + z3 + b1s[j], 0.0f);
    const float* wr = &w2s[j * 64];
#pragma unroll
    for (int j2 = 0; j2 < 64; j2++) h[j2] = fmaf(z, wr[j2], h[j2]);
  }

  float o[16];
#pragma unroll
  for (int t = 0; t < 16; t++) o[t] = cb2s[t];

  for (int j = 0; j < 64; j++) {
    const float* wc = &cw1s[j * 64];
    float z0 = 0.f, z1 = 0.f, z2 = 0.f, z3 = 0.f;
#pragma unroll
    for (int k = 0; k < 64; k += 4) {
      z0 = fmaf(h[k + 0], wc[k + 0], z0);
      z1 = fmaf(h[k + 1], wc[k + 1], z1);
      z2 = fmaf(h[k + 2], wc[k + 2], z2);
      z3 = fmaf(h[k + 3], wc[k + 3], z3);
    }
    const float z = fmaxf(z0 + z1 + z2 + z3 + cb1s[j], 0.0f);
    const float* wr = &cw2s[j * 16];
#pragma unroll
    for (int t = 0; t < 16; t++) o[t] = fmaf(z, wr[t], o[t]);
  }

  float4* op = reinterpret_cast<float4*>(out + (long)node * 16);
#pragma unroll
  for (int q = 0; q < 4; q++)
    op[q] = make_float4(o[q * 4], o[q * 4 + 1], o[q * 4 + 2], o[q * 4 + 3]);
}

extern "C" void kernel_launch(void* const* d_in, const int* in_sizes, int n_in,
                              void* d_out, int out_size, void* d_ws,
                              size_t ws_size, hipStream_t stream) {
  const float* x = (const float*)d_in[0];
  const int* ei = (const int*)d_in[1];
  const float* w1_0 = (const float*)d_in[2];
  const float* b1_0 = (const float*)d_in[3];
  const float* w2_0 = (const float*)d_in[4];
  const float* b2_0 = (const float*)d_in[5];
  const float* w1_1 = (const float*)d_in[6];
  const float* b1_1 = (const float*)d_in[7];
  const float* w2_1 = (const float*)d_in[8];
  const float* b2_1 = (const float*)d_in[9];
  const float* cw1 = (const float*)d_in[10];
  const float* cb1 = (const float*)d_in[11];
  const float* cw2 = (const float*)d_in[12];
  const float* cb2 = (const float*)d_in[13];

  const int n = in_sizes[0] / 32;  // nodes
  const int ne = in_sizes[1] / 2;  // edges
  const int* src = ei;
  const int* dst = ei + ne;

  const int nchunks = (n + 1023) / 1024;            // scan chunks
  const int nbuck = (n + NODES_PER_BUCKET - 1) / NODES_PER_BUCKET;

  // Workspace layout (agg0 and agg1 share one region; agg0 dead after mlp0)
  float* aggr = (float*)d_ws;                     // n*64 (union)
  float* agg0 = aggr;                             // n*32 view
  float* agg1 = aggr;                             // n*64 view
  float* h0 = aggr + (size_t)n * 64;              // n*64
  int2* sorted = (int2*)(h0 + (size_t)n * 64);    // ne int2 (8B aligned)
  int* deg = (int*)(sorted + ne);                 // n
  int* off = deg + n;                             // n+1
  int* partial = off + n + 1;                     // nchunks (<=1024)
  int* bcur = partial + 1024;                     // nbuck*16 (padded)
  int* csr = bcur + (size_t)nbuck * 16;           // ne

  // --- CSR build ---
  hipMemsetAsync(deg, 0, (size_t)n * sizeof(int), stream);
  {
    int blocks = (ne + 255) / 256;
    if (blocks > 2048) blocks = 2048;
    count_deg_kernel<<<blocks, 256, 0, stream>>>(dst, deg, ne);
  }
  scan1_kernel<<<nchunks, 1024, 0, stream>>>(deg, off, partial, n);
  scan2_kernel<<<1, 1024, 0, stream>>>(partial, nchunks);
  scan3_kernel<<<(n + 255) / 256, 256, 0, stream>>>(off, partial, bcur, n, ne);
  {
    int blocks = (ne + 255) / 256;
    if (blocks > 2048) blocks = 2048;
    partition_kernel<<<blocks, 256, 0, stream>>>(src, dst, bcur, sorted, ne);
  }
  fill_bucket_kernel<<<nbuck, 256, 0, stream>>>(sorted, off, csr, n);

  // --- Layer 0 ---
  gather_kernel<8><<<((size_t)n * 8 + 255) / 256, 256, 0, stream>>>(
      x, off, csr, agg0, n);
  const int nb = (n + 255) / 256;
  mlp0_kernel<<<nb, 256, 0, stream>>>(agg0, w1_0, b1_0, w2_0, b2_0, h0, n);

  // --- Layer 1 + classifier ---
  gather_kernel<16><<<((size_t)n * 16 + 255) / 256, 256, 0, stream>>>(
      h0, off, csr, agg1, n);
  mlp1_cls_kernel<<<nb, 256, 0, stream>>>(agg1, w1_1, b1_1, w2_1, b2_1, cw1,
                                          cb1, cw2, cb2, (float*)d_out, n);
}

// Round 4
// 291.166 us; speedup vs baseline: 7.2927x; 1.3559x over previous
//
#include <hip/hip_runtime.h>

// ---------------------------------------------------------------------------
// TreeConv GNN. R3: CSR build restructured for dense, line-local writes.
//   bucket_hist (391 coarse buckets) -> bucket_scan -> chunked LDS partition
//   (packed 4B entries, bin-major copy-out in contiguous runs) -> per-bucket
//   fill (derives per-node off[] locally, csr writes in 16KB L2-local region)
// Gather + MLP kernels unchanged.
// Packing: src in bits [0,17), dst&255 in bits [17,25). Requires n < 2^17.
// ---------------------------------------------------------------------------

#define NPB 256       // nodes per bucket; bucket id = dst >> 8
#define NBMAX 512     // max buckets (n <= 131072)
#define CHUNK 8192    // edges per partition block

__global__ __launch_bounds__(256) void bucket_hist_kernel(
    const int* __restrict__ dst, int* __restrict__ bcnt, int ne, int nb) {
  __shared__ int h[NBMAX];
  for (int i = threadIdx.x; i < nb; i += 256) h[i] = 0;
  __syncthreads();
  for (int e = blockIdx.x * 256 + threadIdx.x; e < ne; e += gridDim.x * 256)
    atomicAdd(&h[dst[e] >> 8], 1);
  __syncthreads();
  for (int i = threadIdx.x; i < nb; i += 256) {
    const int c = h[i];
    if (c) atomicAdd(&bcnt[i], c);
  }
}

// One block, 512 threads: exclusive scan of bcnt[0..nb) -> boff, init bcur.
__global__ __launch_bounds__(512) void bucket_scan_kernel(
    const int* __restrict__ bcnt, int* __restrict__ boff,
    int* __restrict__ bcur, int nb, int ne) {
  __shared__ int wsum[8];
  const int lane = threadIdx.x & 63;
  const int wid = threadIdx.x >> 6;
  const int v = (threadIdx.x < nb) ? bcnt[threadIdx.x] : 0;
  int x = v;
#pragma unroll
  for (int s = 1; s < 64; s <<= 1) {
    int t = __shfl_up(x, s, 64);
    if (lane >= s) x += t;
  }
  if (lane == 63) wsum[wid] = x;
  __syncthreads();
  if (wid == 0 && lane < 8) {
    int y = wsum[lane];
#pragma unroll
    for (int s = 1; s < 8; s <<= 1) {
      int t = __shfl_up(y, s, 64);
      if (lane >= s) y += t;
    }
    wsum[lane] = y;
  }
  __syncthreads();
  const int wbase = (wid == 0) ? 0 : wsum[wid - 1];
  const int excl = wbase + x - v;
  if (threadIdx.x < nb) {
    boff[threadIdx.x] = excl;
    bcur[threadIdx.x] = excl;
  }
  if (threadIdx.x == 0) boff[nb] = ne;
}

// Chunked partition: LDS hist+scan, bin-ordered LDS staging of packed
// entries, per-bin global claims, bin-major contiguous copy-out.
__global__ __launch_bounds__(256) void partition_kernel(
    const int* __restrict__ src, const int* __restrict__ dst,
    int* __restrict__ bcur, int* __restrict__ sorted, int ne, int nb) {
  __shared__ int hist[NBMAX];
  __shared__ int lbase[NBMAX];
  __shared__ int gbase[NBMAX];
  __shared__ int cur[NBMAX];
  __shared__ int vals[CHUNK];
  __shared__ unsigned short bins[CHUNK];

  const int tid = threadIdx.x;
  const int e0 = blockIdx.x * CHUNK;
  const int m = min(CHUNK, ne - e0);

  for (int i = tid; i < nb; i += 256) hist[i] = 0;
  __syncthreads();

  // pass 1: histogram
  for (int i = tid; i < m; i += 256) atomicAdd(&hist[dst[e0 + i] >> 8], 1);
  __syncthreads();

  // exclusive scan of hist -> lbase (wave 0 only, 8 bins per lane)
  if (tid < 64) {
    int v8[8];
    int tot = 0;
#pragma unroll
    for (int k = 0; k < 8; k++) {
      const int b = tid * 8 + k;
      v8[k] = (b < nb) ? hist[b] : 0;
      tot += v8[k];
    }
    int x = tot;
#pragma unroll
    for (int s = 1; s < 64; s <<= 1) {
      int t = __shfl_up(x, s, 64);
      if ((tid & 63) >= s) x += t;
    }
    int run = x - tot;  // exclusive base for this lane's bins
#pragma unroll
    for (int k = 0; k < 8; k++) {
      const int b = tid * 8 + k;
      if (b < nb) {
        lbase[b] = run;
        run += v8[k];
      }
    }
  }
  __syncthreads();

  // claim global runs, init local cursors
  for (int b = tid; b < nb; b += 256) {
    const int c = hist[b];
    cur[b] = lbase[b];
    gbase[b] = c ? atomicAdd(&bcur[b], c) : 0;
  }
  __syncthreads();

  // pass 2: place packed entries bin-ordered in LDS
  for (int i = tid; i < m; i += 256) {
    const int s = src[e0 + i];
    const int d = dst[e0 + i];
    const int b = d >> 8;
    const int p = atomicAdd(&cur[b], 1);
    vals[p] = s | ((d & 255) << 17);
    bins[p] = (unsigned short)b;
  }
  __syncthreads();

  // copy-out: consecutive i in the same bin -> consecutive global addrs
  for (int i = tid; i < m; i += 256) {
    const int b = bins[i];
    sorted[gbase[b] + (i - lbase[b])] = vals[i];
  }
}

// One block per bucket: per-node hist+scan in LDS, write off[] coalesced,
// place src into csr (writes confined to this bucket's 16KB region).
__global__ __launch_bounds__(256) void fill_bucket_kernel(
    const int* __restrict__ sorted, const int* __restrict__ boff,
    int* __restrict__ off, int* __restrict__ csr, int n, int ne) {
  __shared__ int hist[NPB];
  __shared__ int cur[NPB];
  __shared__ int wsum[4];
  const int tid = threadIdx.x;
  const int b = blockIdx.x;
  const int e0 = boff[b];
  const int m = boff[b + 1] - e0;

  hist[tid] = 0;
  __syncthreads();
  for (int i = tid; i < m; i += 256) atomicAdd(&hist[sorted[e0 + i] >> 17], 1);
  __syncthreads();

  const int lane = tid & 63;
  const int wid = tid >> 6;
  const int v = hist[tid];
  int x = v;
#pragma unroll
  for (int s = 1; s < 64; s <<= 1) {
    int t = __shfl_up(x, s, 64);
    if (lane >= s) x += t;
  }
  if (lane == 63) wsum[wid] = x;
  __syncthreads();
  if (tid == 0) {
    int s = 0;
#pragma unroll
    for (int k = 0; k < 4; k++) {
      const int t = wsum[k];
      wsum[k] = s;
      s += t;
    }
  }
  __syncthreads();
  const int excl = wsum[wid] + x - v;
  cur[tid] = excl;
  const int node = b * NPB + tid;
  if (node < n) off[node] = e0 + excl;
  if (b == 0 && tid == 0) off[n] = ne;
  __syncthreads();

  for (int i = tid; i < m; i += 256) {
    const int pv = sorted[e0 + i];
    const int r = atomicAdd(&cur[pv >> 17], 1);
    csr[e0 + r] = pv & 0x1FFFF;
  }
}

// agg[node] = h[node] + sum_{e in CSR[node]} h[csr[e]]
template <int L>
__global__ __launch_bounds__(256) void gather_kernel(
    const float* __restrict__ h, const int* __restrict__ off,
    const int* __restrict__ csr, float* __restrict__ agg, int n_nodes) {
  const int gid = (blockIdx.x * 256 + threadIdx.x) / L;
  const int lane = threadIdx.x & (L - 1);
  if (gid >= n_nodes) return;
  constexpr int D = L * 4;
  float4 acc =
      *reinterpret_cast<const float4*>(h + (size_t)gid * D + lane * 4);
  const int e0 = off[gid], e1 = off[gid + 1];
  for (int e = e0; e < e1; ++e) {
    const int s = csr[e];
    const float4 v =
        *reinterpret_cast<const float4*>(h + (size_t)s * D + lane * 4);
    acc.x += v.x; acc.y += v.y; acc.z += v.z; acc.w += v.w;
  }
  *reinterpret_cast<float4*>(agg + (size_t)gid * D + lane * 4) = acc;
}

// Layer 0: h0 = relu(agg0 @ w1 + b1) @ w2 + b2   (32 -> 64 -> 64)
__global__ __launch_bounds__(256) void mlp0_kernel(
    const float* __restrict__ agg, const float* __restrict__ w1,
    const float* __restrict__ b1, const float* __restrict__ w2,
    const float* __restrict__ b2, float* __restrict__ h0, int n_nodes) {
  __shared__ float w1s[32 * 64];  // transposed
  __shared__ float w2s[64 * 64];  // row-major
  __shared__ float b1s[64], b2s[64];
  for (int i = threadIdx.x; i < 32 * 64; i += 256) {
    int k = i >> 6, j = i & 63;
    w1s[j * 32 + k] = w1[i];
  }
  for (int i = threadIdx.x; i < 64 * 64; i += 256) w2s[i] = w2[i];
  if (threadIdx.x < 64) {
    b1s[threadIdx.x] = b1[threadIdx.x];
    b2s[threadIdx.x] = b2[threadIdx.x];
  }
  __syncthreads();

  const int node = blockIdx.x * 256 + threadIdx.x;
  if (node >= n_nodes) return;

  float a[32];
  const float4* ap = reinterpret_cast<const float4*>(agg + (long)node * 32);
#pragma unroll
  for (int q = 0; q < 8; q++) {
    float4 v = ap[q];
    a[q * 4 + 0] = v.x; a[q * 4 + 1] = v.y;
    a[q * 4 + 2] = v.z; a[q * 4 + 3] = v.w;
  }
  float h[64];
#pragma unroll
  for (int j2 = 0; j2 < 64; j2++) h[j2] = b2s[j2];

  for (int j = 0; j < 64; j++) {
    const float* wc = &w1s[j * 32];
    float z0 = 0.f, z1 = 0.f, z2 = 0.f, z3 = 0.f;
#pragma unroll
    for (int k = 0; k < 32; k += 4) {
      z0 = fmaf(a[k + 0], wc[k + 0], z0);
      z1 = fmaf(a[k + 1], wc[k + 1], z1);
      z2 = fmaf(a[k + 2], wc[k + 2], z2);
      z3 = fmaf(a[k + 3], wc[k + 3], z3);
    }
    const float z = fmaxf(z0 + z1 + z2 + z3 + b1s[j], 0.0f);
    const float* wr = &w2s[j * 64];
#pragma unroll
    for (int j2 = 0; j2 < 64; j2++) h[j2] = fmaf(z, wr[j2], h[j2]);
  }

  float4* hp = reinterpret_cast<float4*>(h0 + (long)node * 64);
#pragma unroll
  for (int q = 0; q < 16; q++)
    hp[q] = make_float4(h[q * 4], h[q * 4 + 1], h[q * 4 + 2], h[q * 4 + 3]);
}

// Layer 1 + classifier fused.
__global__ __launch_bounds__(256) void mlp1_cls_kernel(
    const float* __restrict__ agg, const float* __restrict__ w1,
    const float* __restrict__ b1, const float* __restrict__ w2,
    const float* __restrict__ b2, const float* __restrict__ cw1,
    const float* __restrict__ cb1, const float* __restrict__ cw2,
    const float* __restrict__ cb2, float* __restrict__ out, int n_nodes) {
  __shared__ float w1s[64 * 64];   // transposed
  __shared__ float w2s[64 * 64];   // row-major
  __shared__ float cw1s[64 * 64];  // transposed
  __shared__ float cw2s[64 * 16];  // row-major
  __shared__ float b1s[64], b2s[64], cb1s[64], cb2s[16];
  for (int i = threadIdx.x; i < 4096; i += 256) {
    int k = i >> 6, j = i & 63;
    w1s[j * 64 + k] = w1[i];
    cw1s[j * 64 + k] = cw1[i];
    w2s[i] = w2[i];
  }
  for (int i = threadIdx.x; i < 1024; i += 256) cw2s[i] = cw2[i];
  if (threadIdx.x < 64) {
    b1s[threadIdx.x] = b1[threadIdx.x];
    b2s[threadIdx.x] = b2[threadIdx.x];
    cb1s[threadIdx.x] = cb1[threadIdx.x];
  }
  if (threadIdx.x < 16) cb2s[threadIdx.x] = cb2[threadIdx.x];
  __syncthreads();

  const int node = blockIdx.x * 256 + threadIdx.x;
  if (node >= n_nodes) return;

  float a[64];
  const float4* ap = reinterpret_cast<const float4*>(agg + (long)node * 64);
#pragma unroll
  for (int q = 0; q < 16; q++) {
    float4 v = ap[q];
    a[q * 4 + 0] = v.x; a[q * 4 + 1] = v.y;
    a[q * 4 + 2] = v.z; a[q * 4 + 3] = v.w;
  }

  float h[64];
#pragma unroll
  for (int j2 = 0; j2 < 64; j2++) h[j2] = b2s[j2];

  for (int j = 0; j < 64; j++) {
    const float* wc = &w1s[j * 64];
    float z0 = 0.f, z1 = 0.f, z2 = 0.f, z3 = 0.f;
#pragma unroll
    for (int k = 0; k < 64; k += 4) {
      z0 = fmaf(a[k + 0], wc[k + 0], z0);
      z1 = fmaf(a[k + 1], wc[k + 1], z1);
      z2 = fmaf(a[k + 2], wc[k + 2], z2);
      z3 = fmaf(a[k + 3], wc[k + 3], z3);
    }
    const float z = fmaxf(z0 + z1 + z2 + z3 + b1s[j], 0.0f);
    const float* wr = &w2s[j * 64];
#pragma unroll
    for (int j2 = 0; j2 < 64; j2++) h[j2] = fmaf(z, wr[j2], h[j2]);
  }

  float o[16];
#pragma unroll
  for (int t = 0; t < 16; t++) o[t] = cb2s[t];

  for (int j = 0; j < 64; j++) {
    const float* wc = &cw1s[j * 64];
    float z0 = 0.f, z1 = 0.f, z2 = 0.f, z3 = 0.f;
#pragma unroll
    for (int k = 0; k < 64; k += 4) {
      z0 = fmaf(h[k + 0], wc[k + 0], z0);
      z1 = fmaf(h[k + 1], wc[k + 1], z1);
      z2 = fmaf(h[k + 2], wc[k + 2], z2);
      z3 = fmaf(h[k + 3], wc[k + 3], z3);
    }
    const float z = fmaxf(z0 + z1 + z2 + z3 + cb1s[j], 0.0f);
    const float* wr = &cw2s[j * 16];
#pragma unroll
    for (int t = 0; t < 16; t++) o[t] = fmaf(z, wr[t], o[t]);
  }

  float4* op = reinterpret_cast<float4*>(out + (long)node * 16);
#pragma unroll
  for (int q = 0; q < 4; q++)
    op[q] = make_float4(o[q * 4], o[q * 4 + 1], o[q * 4 + 2], o[q * 4 + 3]);
}

extern "C" void kernel_launch(void* const* d_in, const int* in_sizes, int n_in,
                              void* d_out, int out_size, void* d_ws,
                              size_t ws_size, hipStream_t stream) {
  const float* x = (const float*)d_in[0];
  const int* ei = (const int*)d_in[1];
  const float* w1_0 = (const float*)d_in[2];
  const float* b1_0 = (const float*)d_in[3];
  const float* w2_0 = (const float*)d_in[4];
  const float* b2_0 = (const float*)d_in[5];
  const float* w1_1 = (const float*)d_in[6];
  const float* b1_1 = (const float*)d_in[7];
  const float* w2_1 = (const float*)d_in[8];
  const float* b2_1 = (const float*)d_in[9];
  const float* cw1 = (const float*)d_in[10];
  const float* cb1 = (const float*)d_in[11];
  const float* cw2 = (const float*)d_in[12];
  const float* cb2 = (const float*)d_in[13];

  const int n = in_sizes[0] / 32;  // nodes (< 2^17 for packing)
  const int ne = in_sizes[1] / 2;  // edges
  const int* src = ei;
  const int* dst = ei + ne;
  const int nb = (n + NPB - 1) / NPB;

  // Workspace layout (agg0/agg1 share one region)
  float* aggr = (float*)d_ws;                   // n*64 (union)
  float* h0 = aggr + (size_t)n * 64;            // n*64
  int* sorted = (int*)(h0 + (size_t)n * 64);    // ne
  int* csr = sorted + ne;                       // ne
  int* off = csr + ne;                          // n+1
  int* bcnt = off + n + 1;                      // nb
  int* boff = bcnt + nb;                        // nb+1
  int* bcur = boff + nb + 1;                    // nb

  // --- CSR build ---
  hipMemsetAsync(bcnt, 0, (size_t)nb * sizeof(int), stream);
  bucket_hist_kernel<<<64, 256, 0, stream>>>(dst, bcnt, ne, nb);
  bucket_scan_kernel<<<1, 512, 0, stream>>>(bcnt, boff, bcur, nb, ne);
  partition_kernel<<<(ne + CHUNK - 1) / CHUNK, 256, 0, stream>>>(
      src, dst, bcur, sorted, ne, nb);
  fill_bucket_kernel<<<nb, 256, 0, stream>>>(sorted, boff, off, csr, n, ne);

  // --- Layer 0 ---
  gather_kernel<8><<<((size_t)n * 8 + 255) / 256, 256, 0, stream>>>(
      x, off, csr, aggr, n);
  const int nblk = (n + 255) / 256;
  mlp0_kernel<<<nblk, 256, 0, stream>>>(aggr, w1_0, b1_0, w2_0, b2_0, h0, n);

  // --- Layer 1 + classifier ---
  gather_kernel<16><<<((size_t)n * 16 + 255) / 256, 256, 0, stream>>>(
      h0, off, csr, aggr, n);
  mlp1_cls_kernel<<<nblk, 256, 0, stream>>>(aggr, w1_1, b1_1, w2_1, b2_1, cw1,
                                            cb1, cw2, cb2, (float*)d_out, n);
}

// Round 5
// 262.702 us; speedup vs baseline: 8.0829x; 1.1084x over previous
//
#include <hip/hip_runtime.h>

// ---------------------------------------------------------------------------
// TreeConv GNN. R4: register-tiled MLP GEMMs.
//   mlp_pair<K1>: C = relu(A@W1+b1)@W2+b2 on 128-node tiles; thread owns a
//   4-node x 8-out register tile; A staged transposed [K][128] in LDS; z
//   round-trips through the same LDS region. cls_tiled: 64->64(relu)->16.
// CSR build + gather unchanged from R3 (bucket_hist grid 64->220).
// ---------------------------------------------------------------------------

#define NPB 256       // nodes per bucket; bucket id = dst >> 8
#define NBMAX 512     // max buckets (n <= 131072)
#define CHUNK 8192    // edges per partition block

__global__ __launch_bounds__(256) void bucket_hist_kernel(
    const int* __restrict__ dst, int* __restrict__ bcnt, int ne, int nb) {
  __shared__ int h[NBMAX];
  for (int i = threadIdx.x; i < nb; i += 256) h[i] = 0;
  __syncthreads();
  for (int e = blockIdx.x * 256 + threadIdx.x; e < ne; e += gridDim.x * 256)
    atomicAdd(&h[dst[e] >> 8], 1);
  __syncthreads();
  for (int i = threadIdx.x; i < nb; i += 256) {
    const int c = h[i];
    if (c) atomicAdd(&bcnt[i], c);
  }
}

__global__ __launch_bounds__(512) void bucket_scan_kernel(
    const int* __restrict__ bcnt, int* __restrict__ boff,
    int* __restrict__ bcur, int nb, int ne) {
  __shared__ int wsum[8];
  const int lane = threadIdx.x & 63;
  const int wid = threadIdx.x >> 6;
  const int v = (threadIdx.x < nb) ? bcnt[threadIdx.x] : 0;
  int x = v;
#pragma unroll
  for (int s = 1; s < 64; s <<= 1) {
    int t = __shfl_up(x, s, 64);
    if (lane >= s) x += t;
  }
  if (lane == 63) wsum[wid] = x;
  __syncthreads();
  if (wid == 0 && lane < 8) {
    int y = wsum[lane];
#pragma unroll
    for (int s = 1; s < 8; s <<= 1) {
      int t = __shfl_up(y, s, 64);
      if (lane >= s) y += t;
    }
    wsum[lane] = y;
  }
  __syncthreads();
  const int wbase = (wid == 0) ? 0 : wsum[wid - 1];
  const int excl = wbase + x - v;
  if (threadIdx.x < nb) {
    boff[threadIdx.x] = excl;
    bcur[threadIdx.x] = excl;
  }
  if (threadIdx.x == 0) boff[nb] = ne;
}

__global__ __launch_bounds__(256) void partition_kernel(
    const int* __restrict__ src, const int* __restrict__ dst,
    int* __restrict__ bcur, int* __restrict__ sorted, int ne, int nb) {
  __shared__ int hist[NBMAX];
  __shared__ int lbase[NBMAX];
  __shared__ int gbase[NBMAX];
  __shared__ int cur[NBMAX];
  __shared__ int vals[CHUNK];
  __shared__ unsigned short bins[CHUNK];

  const int tid = threadIdx.x;
  const int e0 = blockIdx.x * CHUNK;
  const int m = min(CHUNK, ne - e0);

  for (int i = tid; i < nb; i += 256) hist[i] = 0;
  __syncthreads();
  for (int i = tid; i < m; i += 256) atomicAdd(&hist[dst[e0 + i] >> 8], 1);
  __syncthreads();

  if (tid < 64) {
    int v8[8];
    int tot = 0;
#pragma unroll
    for (int k = 0; k < 8; k++) {
      const int b = tid * 8 + k;
      v8[k] = (b < nb) ? hist[b] : 0;
      tot += v8[k];
    }
    int x = tot;
#pragma unroll
    for (int s = 1; s < 64; s <<= 1) {
      int t = __shfl_up(x, s, 64);
      if ((tid & 63) >= s) x += t;
    }
    int run = x - tot;
#pragma unroll
    for (int k = 0; k < 8; k++) {
      const int b = tid * 8 + k;
      if (b < nb) {
        lbase[b] = run;
        run += v8[k];
      }
    }
  }
  __syncthreads();

  for (int b = tid; b < nb; b += 256) {
    const int c = hist[b];
    cur[b] = lbase[b];
    gbase[b] = c ? atomicAdd(&bcur[b], c) : 0;
  }
  __syncthreads();

  for (int i = tid; i < m; i += 256) {
    const int s = src[e0 + i];
    const int d = dst[e0 + i];
    const int b = d >> 8;
    const int p = atomicAdd(&cur[b], 1);
    vals[p] = s | ((d & 255) << 17);
    bins[p] = (unsigned short)b;
  }
  __syncthreads();

  for (int i = tid; i < m; i += 256) {
    const int b = bins[i];
    sorted[gbase[b] + (i - lbase[b])] = vals[i];
  }
}

__global__ __launch_bounds__(256) void fill_bucket_kernel(
    const int* __restrict__ sorted, const int* __restrict__ boff,
    int* __restrict__ off, int* __restrict__ csr, int n, int ne) {
  __shared__ int hist[NPB];
  __shared__ int cur[NPB];
  __shared__ int wsum[4];
  const int tid = threadIdx.x;
  const int b = blockIdx.x;
  const int e0 = boff[b];
  const int m = boff[b + 1] - e0;

  hist[tid] = 0;
  __syncthreads();
  for (int i = tid; i < m; i += 256) atomicAdd(&hist[sorted[e0 + i] >> 17], 1);
  __syncthreads();

  const int lane = tid & 63;
  const int wid = tid >> 6;
  const int v = hist[tid];
  int x = v;
#pragma unroll
  for (int s = 1; s < 64; s <<= 1) {
    int t = __shfl_up(x, s, 64);
    if (lane >= s) x += t;
  }
  if (lane == 63) wsum[wid] = x;
  __syncthreads();
  if (tid == 0) {
    int s = 0;
#pragma unroll
    for (int k = 0; k < 4; k++) {
      const int t = wsum[k];
      wsum[k] = s;
      s += t;
    }
  }
  __syncthreads();
  const int excl = wsum[wid] + x - v;
  cur[tid] = excl;
  const int node = b * NPB + tid;
  if (node < n) off[node] = e0 + excl;
  if (b == 0 && tid == 0) off[n] = ne;
  __syncthreads();

  for (int i = tid; i < m; i += 256) {
    const int pv = sorted[e0 + i];
    const int r = atomicAdd(&cur[pv >> 17], 1);
    csr[e0 + r] = pv & 0x1FFFF;
  }
}

// agg[node] = h[node] + sum_{e in CSR[node]} h[csr[e]]
template <int L>
__global__ __launch_bounds__(256) void gather_kernel(
    const float* __restrict__ h, const int* __restrict__ off,
    const int* __restrict__ csr, float* __restrict__ agg, int n_nodes) {
  const int gid = (blockIdx.x * 256 + threadIdx.x) / L;
  const int lane = threadIdx.x & (L - 1);
  if (gid >= n_nodes) return;
  constexpr int D = L * 4;
  float4 acc =
      *reinterpret_cast<const float4*>(h + (size_t)gid * D + lane * 4);
  const int e0 = off[gid], e1 = off[gid + 1];
  for (int e = e0; e < e1; ++e) {
    const int s = csr[e];
    const float4 v =
        *reinterpret_cast<const float4*>(h + (size_t)s * D + lane * 4);
    acc.x += v.x; acc.y += v.y; acc.z += v.z; acc.w += v.w;
  }
  *reinterpret_cast<float4*>(agg + (size_t)gid * D + lane * 4) = acc;
}

// ---------------------------------------------------------------------------
// Register-tiled fused GEMM pair: out = relu(A@w1 + b1)@w2 + b2
// A: [n x K1], w1: [K1 x 64], w2: [64 x 64], out: [n x 64].
// Tile: 128 nodes. Thread (tm=tid&31, tn=tid>>5) owns nodes 4tm..4tm+3,
// outs 8tn..8tn+7. A staged transposed U[K][128]; z reuses U.
// ---------------------------------------------------------------------------
template <int K1>
__global__ __launch_bounds__(256) void mlp_pair_kernel(
    const float* __restrict__ A, const float* __restrict__ w1,
    const float* __restrict__ b1, const float* __restrict__ w2,
    const float* __restrict__ b2, float* __restrict__ out, int n) {
  __shared__ float U[64 * 128];   // As_T (K1 x 128) then Zs_T (64 x 128)
  __shared__ float W1s[K1 * 64];
  __shared__ float W2s[64 * 64];
  const int tid = threadIdx.x;
  const int n0 = blockIdx.x * 128;

  for (int i = tid; i < K1 * 16; i += 256)
    ((float4*)W1s)[i] = ((const float4*)w1)[i];
  for (int i = tid; i < 1024; i += 256)
    ((float4*)W2s)[i] = ((const float4*)w2)[i];

  constexpr int Q = K1 / 4;  // float4s per A row
  for (int idx = tid; idx < 128 * Q; idx += 256) {
    const int node = idx / Q;
    const int q = idx % Q;
    const int g = n0 + node;
    float4 v = make_float4(0.f, 0.f, 0.f, 0.f);
    if (g < n) v = ((const float4*)A)[(size_t)g * Q + q];
    U[(q * 4 + 0) * 128 + node] = v.x;
    U[(q * 4 + 1) * 128 + node] = v.y;
    U[(q * 4 + 2) * 128 + node] = v.z;
    U[(q * 4 + 3) * 128 + node] = v.w;
  }
  __syncthreads();

  const int tm = tid & 31, tn = tid >> 5;

  // GEMM1 + bias + relu
  float acc[4][8];
  {
    const float4 ba = *(const float4*)(b1 + tn * 8);
    const float4 bb = *(const float4*)(b1 + tn * 8 + 4);
#pragma unroll
    for (int i = 0; i < 4; i++) {
      acc[i][0] = ba.x; acc[i][1] = ba.y; acc[i][2] = ba.z; acc[i][3] = ba.w;
      acc[i][4] = bb.x; acc[i][5] = bb.y; acc[i][6] = bb.z; acc[i][7] = bb.w;
    }
  }
#pragma unroll 8
  for (int k = 0; k < K1; k++) {
    const float4 av = *(const float4*)&U[k * 128 + tm * 4];
    const float4 w0 = *(const float4*)&W1s[k * 64 + tn * 8];
    const float4 w1v = *(const float4*)&W1s[k * 64 + tn * 8 + 4];
    const float a4[4] = {av.x, av.y, av.z, av.w};
    const float wv[8] = {w0.x, w0.y, w0.z, w0.w, w1v.x, w1v.y, w1v.z, w1v.w};
#pragma unroll
    for (int i = 0; i < 4; i++)
#pragma unroll
      for (int j = 0; j < 8; j++) acc[i][j] = fmaf(a4[i], wv[j], acc[i][j]);
  }
#pragma unroll
  for (int i = 0; i < 4; i++)
#pragma unroll
    for (int j = 0; j < 8; j++) acc[i][j] = fmaxf(acc[i][j], 0.f);

  __syncthreads();  // all A reads done; safe to overwrite U with z
#pragma unroll
  for (int j = 0; j < 8; j++)
#pragma unroll
    for (int i = 0; i < 4; i++)
      U[(tn * 8 + j) * 128 + tm * 4 + i] = acc[i][j];
  __syncthreads();

  // GEMM2 + bias
  float acc2[4][8];
  {
    const float4 ba = *(const float4*)(b2 + tn * 8);
    const float4 bb = *(const float4*)(b2 + tn * 8 + 4);
#pragma unroll
    for (int i = 0; i < 4; i++) {
      acc2[i][0] = ba.x; acc2[i][1] = ba.y; acc2[i][2] = ba.z; acc2[i][3] = ba.w;
      acc2[i][4] = bb.x; acc2[i][5] = bb.y; acc2[i][6] = bb.z; acc2[i][7] = bb.w;
    }
  }
#pragma unroll 8
  for (int k = 0; k < 64; k++) {
    const float4 av = *(const float4*)&U[k * 128 + tm * 4];
    const float4 w0 = *(const float4*)&W2s[k * 64 + tn * 8];
    const float4 w1v = *(const float4*)&W2s[k * 64 + tn * 8 + 4];
    const float a4[4] = {av.x, av.y, av.z, av.w};
    const float wv[8] = {w0.x, w0.y, w0.z, w0.w, w1v.x, w1v.y, w1v.z, w1v.w};
#pragma unroll
    for (int i = 0; i < 4; i++)
#pragma unroll
      for (int j = 0; j < 8; j++) acc2[i][j] = fmaf(a4[i], wv[j], acc2[i][j]);
  }

#pragma unroll
  for (int i = 0; i < 4; i++) {
    const int g = n0 + tm * 4 + i;
    if (g < n) {
      ((float4*)out)[(size_t)g * 16 + tn * 2] =
          make_float4(acc2[i][0], acc2[i][1], acc2[i][2], acc2[i][3]);
      ((float4*)out)[(size_t)g * 16 + tn * 2 + 1] =
          make_float4(acc2[i][4], acc2[i][5], acc2[i][6], acc2[i][7]);
    }
  }
}

// Classifier: out = relu(A@cw1 + cb1)@cw2 + cb2,  A:[n x 64], out:[n x 16].
__global__ __launch_bounds__(256) void cls_tiled_kernel(
    const float* __restrict__ A, const float* __restrict__ w1,
    const float* __restrict__ b1, const float* __restrict__ w2,
    const float* __restrict__ b2, float* __restrict__ out, int n) {
  __shared__ float U[64 * 128];
  __shared__ float W1s[64 * 64];
  __shared__ float W2s[64 * 16];
  const int tid = threadIdx.x;
  const int n0 = blockIdx.x * 128;

  for (int i = tid; i < 1024; i += 256)
    ((float4*)W1s)[i] = ((const float4*)w1)[i];
  for (int i = tid; i < 256; i += 256)
    ((float4*)W2s)[i] = ((const float4*)w2)[i];

  for (int idx = tid; idx < 128 * 16; idx += 256) {
    const int node = idx >> 4;
    const int q = idx & 15;
    const int g = n0 + node;
    float4 v = make_float4(0.f, 0.f, 0.f, 0.f);
    if (g < n) v = ((const float4*)A)[(size_t)g * 16 + q];
    U[(q * 4 + 0) * 128 + node] = v.x;
    U[(q * 4 + 1) * 128 + node] = v.y;
    U[(q * 4 + 2) * 128 + node] = v.z;
    U[(q * 4 + 3) * 128 + node] = v.w;
  }
  __syncthreads();

  const int tm = tid & 31, tn = tid >> 5;

  float acc[4][8];
  {
    const float4 ba = *(const float4*)(b1 + tn * 8);
    const float4 bb = *(const float4*)(b1 + tn * 8 + 4);
#pragma unroll
    for (int i = 0; i < 4; i++) {
      acc[i][0] = ba.x; acc[i][1] = ba.y; acc[i][2] = ba.z; acc[i][3] = ba.w;
      acc[i][4] = bb.x; acc[i][5] = bb.y; acc[i][6] = bb.z; acc[i][7] = bb.w;
    }
  }
#pragma unroll 8
  for (int k = 0; k < 64; k++) {
    const float4 av = *(const float4*)&U[k * 128 + tm * 4];
    const float4 w0 = *(const float4*)&W1s[k * 64 + tn * 8];
    const float4 w1v = *(const float4*)&W1s[k * 64 + tn * 8 + 4];
    const float a4[4] = {av.x, av.y, av.z, av.w};
    const float wv[8] = {w0.x, w0.y, w0.z, w0.w, w1v.x, w1v.y, w1v.z, w1v.w};
#pragma unroll
    for (int i = 0; i < 4; i++)
#pragma unroll
      for (int j = 0; j < 8; j++) acc[i][j] = fmaf(a4[i], wv[j], acc[i][j]);
  }
#pragma unroll
  for (int i = 0; i < 4; i++)
#pragma unroll
    for (int j = 0; j < 8; j++) acc[i][j] = fmaxf(acc[i][j], 0.f);

  __syncthreads();
#pragma unroll
  for (int j = 0; j < 8; j++)
#pragma unroll
    for (int i = 0; i < 4; i++)
      U[(tn * 8 + j) * 128 + tm * 4 + i] = acc[i][j];
  __syncthreads();

  // GEMM2: 64 -> 16, thread owns 4 nodes x 2 outs (cols 2tn, 2tn+1)
  float acc2[4][2];
  {
    const float b0 = b2[tn * 2], b1v = b2[tn * 2 + 1];
#pragma unroll
    for (int i = 0; i < 4; i++) { acc2[i][0] = b0; acc2[i][1] = b1v; }
  }
#pragma unroll 8
  for (int k = 0; k < 64; k++) {
    const float4 av = *(const float4*)&U[k * 128 + tm * 4];
    const float wa = W2s[k * 16 + tn * 2];
    const float wb = W2s[k * 16 + tn * 2 + 1];
    const float a4[4] = {av.x, av.y, av.z, av.w};
#pragma unroll
    for (int i = 0; i < 4; i++) {
      acc2[i][0] = fmaf(a4[i], wa, acc2[i][0]);
      acc2[i][1] = fmaf(a4[i], wb, acc2[i][1]);
    }
  }
#pragma unroll
  for (int i = 0; i < 4; i++) {
    const int g = n0 + tm * 4 + i;
    if (g < n)
      ((float2*)out)[(size_t)g * 8 + tn] = make_float2(acc2[i][0], acc2[i][1]);
  }
}

extern "C" void kernel_launch(void* const* d_in, const int* in_sizes, int n_in,
                              void* d_out, int out_size, void* d_ws,
                              size_t ws_size, hipStream_t stream) {
  const float* x = (const float*)d_in[0];
  const int* ei = (const int*)d_in[1];
  const float* w1_0 = (const float*)d_in[2];
  const float* b1_0 = (const float*)d_in[3];
  const float* w2_0 = (const float*)d_in[4];
  const float* b2_0 = (const float*)d_in[5];
  const float* w1_1 = (const float*)d_in[6];
  const float* b1_1 = (const float*)d_in[7];
  const float* w2_1 = (const float*)d_in[8];
  const float* b2_1 = (const float*)d_in[9];
  const float* cw1 = (const float*)d_in[10];
  const float* cb1 = (const float*)d_in[11];
  const float* cw2 = (const float*)d_in[12];
  const float* cb2 = (const float*)d_in[13];

  const int n = in_sizes[0] / 32;  // nodes (< 2^17 for packing)
  const int ne = in_sizes[1] / 2;  // edges
  const int* src = ei;
  const int* dst = ei + ne;
  const int nb = (n + NPB - 1) / NPB;

  // Workspace layout
  float* aggr = (float*)d_ws;                   // n*64 (agg0/agg1 union)
  float* h0 = aggr + (size_t)n * 64;            // n*64 (h0, then h1 in place)
  int* sorted = (int*)(h0 + (size_t)n * 64);    // ne
  int* csr = sorted + ne;                       // ne
  int* off = csr + ne;                          // n+1
  int* bcnt = off + n + 1;                      // nb
  int* boff = bcnt + nb;                        // nb+1
  int* bcur = boff + nb + 1;                    // nb

  // --- CSR build ---
  hipMemsetAsync(bcnt, 0, (size_t)nb * sizeof(int), stream);
  bucket_hist_kernel<<<220, 256, 0, stream>>>(dst, bcnt, ne, nb);
  bucket_scan_kernel<<<1, 512, 0, stream>>>(bcnt, boff, bcur, nb, ne);
  partition_kernel<<<(ne + CHUNK - 1) / CHUNK, 256, 0, stream>>>(
      src, dst, bcur, sorted, ne, nb);
  fill_bucket_kernel<<<nb, 256, 0, stream>>>(sorted, boff, off, csr, n, ne);

  const int ntile = (n + 127) / 128;

  // --- Layer 0 ---
  gather_kernel<8><<<((size_t)n * 8 + 255) / 256, 256, 0, stream>>>(
      x, off, csr, aggr, n);
  mlp_pair_kernel<32><<<ntile, 256, 0, stream>>>(aggr, w1_0, b1_0, w2_0, b2_0,
                                                 h0, n);

  // --- Layer 1 ---
  gather_kernel<16><<<((size_t)n * 16 + 255) / 256, 256, 0, stream>>>(
      h0, off, csr, aggr, n);
  mlp_pair_kernel<64><<<ntile, 256, 0, stream>>>(aggr, w1_1, b1_1, w2_1, b2_1,
                                                 h0, n);  // h1 -> h0 region

  // --- Classifier ---
  cls_tiled_kernel<<<ntile, 256, 0, stream>>>(h0, cw1, cb1, cw2, cb2,
                                              (float*)d_out, n);
}

// Round 6
// 252.223 us; speedup vs baseline: 8.4186x; 1.0415x over previous
//
#include <hip/hip_runtime.h>

// ---------------------------------------------------------------------------
// TreeConv GNN. R5: bf16-compressed gather operands.
//   Gather is L2-miss-volume bound (R5 profile: 187MB FETCH for 25.6MB src,
//   random 256B rows). Halve bytes/edge: x -> bf16 (tiny pass), mlp0 emits
//   h0 as packed bf16 in its epilogue; gathers read bf16, accumulate fp32.
// CSR build (R3) + register-tiled MLPs (R4) otherwise unchanged.
// ---------------------------------------------------------------------------

#define NPB 256       // nodes per bucket; bucket id = dst >> 8
#define NBMAX 512     // max buckets (n <= 131072)
#define CHUNK 8192    // edges per partition block

__device__ inline unsigned int bfbits(float f) {  // RNE f32 -> bf16 bits
  unsigned int x = __float_as_uint(f);
  return (x + 0x7fffu + ((x >> 16) & 1u)) >> 16;
}
__device__ inline unsigned int packbf(float a, float b) {
  return bfbits(a) | (bfbits(b) << 16);
}
__device__ inline float bflo(unsigned int u) {
  return __uint_as_float(u << 16);
}
__device__ inline float bfhi(unsigned int u) {
  return __uint_as_float(u & 0xffff0000u);
}

__global__ __launch_bounds__(256) void bucket_hist_kernel(
    const int* __restrict__ dst, int* __restrict__ bcnt, int ne, int nb) {
  __shared__ int h[NBMAX];
  for (int i = threadIdx.x; i < nb; i += 256) h[i] = 0;
  __syncthreads();
  for (int e = blockIdx.x * 256 + threadIdx.x; e < ne; e += gridDim.x * 256)
    atomicAdd(&h[dst[e] >> 8], 1);
  __syncthreads();
  for (int i = threadIdx.x; i < nb; i += 256) {
    const int c = h[i];
    if (c) atomicAdd(&bcnt[i], c);
  }
}

__global__ __launch_bounds__(512) void bucket_scan_kernel(
    const int* __restrict__ bcnt, int* __restrict__ boff,
    int* __restrict__ bcur, int nb, int ne) {
  __shared__ int wsum[8];
  const int lane = threadIdx.x & 63;
  const int wid = threadIdx.x >> 6;
  const int v = (threadIdx.x < nb) ? bcnt[threadIdx.x] : 0;
  int x = v;
#pragma unroll
  for (int s = 1; s < 64; s <<= 1) {
    int t = __shfl_up(x, s, 64);
    if (lane >= s) x += t;
  }
  if (lane == 63) wsum[wid] = x;
  __syncthreads();
  if (wid == 0 && lane < 8) {
    int y = wsum[lane];
#pragma unroll
    for (int s = 1; s < 8; s <<= 1) {
      int t = __shfl_up(y, s, 64);
      if (lane >= s) y += t;
    }
    wsum[lane] = y;
  }
  __syncthreads();
  const int wbase = (wid == 0) ? 0 : wsum[wid - 1];
  const int excl = wbase + x - v;
  if (threadIdx.x < nb) {
    boff[threadIdx.x] = excl;
    bcur[threadIdx.x] = excl;
  }
  if (threadIdx.x == 0) boff[nb] = ne;
}

__global__ __launch_bounds__(256) void partition_kernel(
    const int* __restrict__ src, const int* __restrict__ dst,
    int* __restrict__ bcur, int* __restrict__ sorted, int ne, int nb) {
  __shared__ int hist[NBMAX];
  __shared__ int lbase[NBMAX];
  __shared__ int gbase[NBMAX];
  __shared__ int cur[NBMAX];
  __shared__ int vals[CHUNK];
  __shared__ unsigned short bins[CHUNK];

  const int tid = threadIdx.x;
  const int e0 = blockIdx.x * CHUNK;
  const int m = min(CHUNK, ne - e0);

  for (int i = tid; i < nb; i += 256) hist[i] = 0;
  __syncthreads();
  for (int i = tid; i < m; i += 256) atomicAdd(&hist[dst[e0 + i] >> 8], 1);
  __syncthreads();

  if (tid < 64) {
    int v8[8];
    int tot = 0;
#pragma unroll
    for (int k = 0; k < 8; k++) {
      const int b = tid * 8 + k;
      v8[k] = (b < nb) ? hist[b] : 0;
      tot += v8[k];
    }
    int x = tot;
#pragma unroll
    for (int s = 1; s < 64; s <<= 1) {
      int t = __shfl_up(x, s, 64);
      if ((tid & 63) >= s) x += t;
    }
    int run = x - tot;
#pragma unroll
    for (int k = 0; k < 8; k++) {
      const int b = tid * 8 + k;
      if (b < nb) {
        lbase[b] = run;
        run += v8[k];
      }
    }
  }
  __syncthreads();

  for (int b = tid; b < nb; b += 256) {
    const int c = hist[b];
    cur[b] = lbase[b];
    gbase[b] = c ? atomicAdd(&bcur[b], c) : 0;
  }
  __syncthreads();

  for (int i = tid; i < m; i += 256) {
    const int s = src[e0 + i];
    const int d = dst[e0 + i];
    const int b = d >> 8;
    const int p = atomicAdd(&cur[b], 1);
    vals[p] = s | ((d & 255) << 17);
    bins[p] = (unsigned short)b;
  }
  __syncthreads();

  for (int i = tid; i < m; i += 256) {
    const int b = bins[i];
    sorted[gbase[b] + (i - lbase[b])] = vals[i];
  }
}

__global__ __launch_bounds__(256) void fill_bucket_kernel(
    const int* __restrict__ sorted, const int* __restrict__ boff,
    int* __restrict__ off, int* __restrict__ csr, int n, int ne) {
  __shared__ int hist[NPB];
  __shared__ int cur[NPB];
  __shared__ int wsum[4];
  const int tid = threadIdx.x;
  const int b = blockIdx.x;
  const int e0 = boff[b];
  const int m = boff[b + 1] - e0;

  hist[tid] = 0;
  __syncthreads();
  for (int i = tid; i < m; i += 256) atomicAdd(&hist[sorted[e0 + i] >> 17], 1);
  __syncthreads();

  const int lane = tid & 63;
  const int wid = tid >> 6;
  const int v = hist[tid];
  int x = v;
#pragma unroll
  for (int s = 1; s < 64; s <<= 1) {
    int t = __shfl_up(x, s, 64);
    if (lane >= s) x += t;
  }
  if (lane == 63) wsum[wid] = x;
  __syncthreads();
  if (tid == 0) {
    int s = 0;
#pragma unroll
    for (int k = 0; k < 4; k++) {
      const int t = wsum[k];
      wsum[k] = s;
      s += t;
    }
  }
  __syncthreads();
  const int excl = wsum[wid] + x - v;
  cur[tid] = excl;
  const int node = b * NPB + tid;
  if (node < n) off[node] = e0 + excl;
  if (b == 0 && tid == 0) off[n] = ne;
  __syncthreads();

  for (int i = tid; i < m; i += 256) {
    const int pv = sorted[e0 + i];
    const int r = atomicAdd(&cur[pv >> 17], 1);
    csr[e0 + r] = pv & 0x1FFFF;
  }
}

// f32 -> packed bf16 (RNE), 4 floats per thread
__global__ __launch_bounds__(256) void f32_to_bf16_kernel(
    const float4* __restrict__ in, uint2* __restrict__ out, int n4) {
  const int i = blockIdx.x * 256 + threadIdx.x;
  if (i < n4) {
    const float4 v = in[i];
    out[i] = make_uint2(packbf(v.x, v.y), packbf(v.z, v.w));
  }
}

// agg[node] = h[node] + sum_{e in CSR[node]} h[csr[e]]   (h in packed bf16)
// L lanes per node; lane owns 4 elems (one uint2 = 4 bf16). D = 4*L.
template <int L>
__global__ __launch_bounds__(256) void gather_bf16_kernel(
    const uint2* __restrict__ hbf, const int* __restrict__ off,
    const int* __restrict__ csr, float* __restrict__ agg, int n_nodes) {
  const int gid = (blockIdx.x * 256 + threadIdx.x) / L;
  const int lane = threadIdx.x & (L - 1);
  if (gid >= n_nodes) return;
  uint2 v = hbf[(size_t)gid * L + lane];
  float a0 = bflo(v.x), a1 = bfhi(v.x), a2 = bflo(v.y), a3 = bfhi(v.y);
  const int e0 = off[gid], e1 = off[gid + 1];
  for (int e = e0; e < e1; ++e) {
    const int s = csr[e];
    v = hbf[(size_t)s * L + lane];
    a0 += bflo(v.x); a1 += bfhi(v.x); a2 += bflo(v.y); a3 += bfhi(v.y);
  }
  *reinterpret_cast<float4*>(agg + (size_t)gid * 4 * L + lane * 4) =
      make_float4(a0, a1, a2, a3);
}

// ---------------------------------------------------------------------------
// Register-tiled fused GEMM pair: out = relu(A@w1 + b1)@w2 + b2
// A: [n x K1] f32, out: [n x 64] (f32, or packed bf16 when OUTBF).
// ---------------------------------------------------------------------------
template <int K1, bool OUTBF>
__global__ __launch_bounds__(256) void mlp_pair_kernel(
    const float* __restrict__ A, const float* __restrict__ w1,
    const float* __restrict__ b1, const float* __restrict__ w2,
    const float* __restrict__ b2, void* __restrict__ out, int n) {
  __shared__ float U[64 * 128];   // As_T (K1 x 128) then Zs_T (64 x 128)
  __shared__ float W1s[K1 * 64];
  __shared__ float W2s[64 * 64];
  const int tid = threadIdx.x;
  const int n0 = blockIdx.x * 128;

  for (int i = tid; i < K1 * 16; i += 256)
    ((float4*)W1s)[i] = ((const float4*)w1)[i];
  for (int i = tid; i < 1024; i += 256)
    ((float4*)W2s)[i] = ((const float4*)w2)[i];

  constexpr int Q = K1 / 4;
  for (int idx = tid; idx < 128 * Q; idx += 256) {
    const int node = idx / Q;
    const int q = idx % Q;
    const int g = n0 + node;
    float4 v = make_float4(0.f, 0.f, 0.f, 0.f);
    if (g < n) v = ((const float4*)A)[(size_t)g * Q + q];
    U[(q * 4 + 0) * 128 + node] = v.x;
    U[(q * 4 + 1) * 128 + node] = v.y;
    U[(q * 4 + 2) * 128 + node] = v.z;
    U[(q * 4 + 3) * 128 + node] = v.w;
  }
  __syncthreads();

  const int tm = tid & 31, tn = tid >> 5;

  float acc[4][8];
  {
    const float4 ba = *(const float4*)(b1 + tn * 8);
    const float4 bb = *(const float4*)(b1 + tn * 8 + 4);
#pragma unroll
    for (int i = 0; i < 4; i++) {
      acc[i][0] = ba.x; acc[i][1] = ba.y; acc[i][2] = ba.z; acc[i][3] = ba.w;
      acc[i][4] = bb.x; acc[i][5] = bb.y; acc[i][6] = bb.z; acc[i][7] = bb.w;
    }
  }
#pragma unroll 8
  for (int k = 0; k < K1; k++) {
    const float4 av = *(const float4*)&U[k * 128 + tm * 4];
    const float4 w0 = *(const float4*)&W1s[k * 64 + tn * 8];
    const float4 w1v = *(const float4*)&W1s[k * 64 + tn * 8 + 4];
    const float a4[4] = {av.x, av.y, av.z, av.w};
    const float wv[8] = {w0.x, w0.y, w0.z, w0.w, w1v.x, w1v.y, w1v.z, w1v.w};
#pragma unroll
    for (int i = 0; i < 4; i++)
#pragma unroll
      for (int j = 0; j < 8; j++) acc[i][j] = fmaf(a4[i], wv[j], acc[i][j]);
  }
#pragma unroll
  for (int i = 0; i < 4; i++)
#pragma unroll
    for (int j = 0; j < 8; j++) acc[i][j] = fmaxf(acc[i][j], 0.f);

  __syncthreads();
#pragma unroll
  for (int j = 0; j < 8; j++)
#pragma unroll
    for (int i = 0; i < 4; i++)
      U[(tn * 8 + j) * 128 + tm * 4 + i] = acc[i][j];
  __syncthreads();

  float acc2[4][8];
  {
    const float4 ba = *(const float4*)(b2 + tn * 8);
    const float4 bb = *(const float4*)(b2 + tn * 8 + 4);
#pragma unroll
    for (int i = 0; i < 4; i++) {
      acc2[i][0] = ba.x; acc2[i][1] = ba.y; acc2[i][2] = ba.z; acc2[i][3] = ba.w;
      acc2[i][4] = bb.x; acc2[i][5] = bb.y; acc2[i][6] = bb.z; acc2[i][7] = bb.w;
    }
  }
#pragma unroll 8
  for (int k = 0; k < 64; k++) {
    const float4 av = *(const float4*)&U[k * 128 + tm * 4];
    const float4 w0 = *(const float4*)&W2s[k * 64 + tn * 8];
    const float4 w1v = *(const float4*)&W2s[k * 64 + tn * 8 + 4];
    const float a4[4] = {av.x, av.y, av.z, av.w};
    const float wv[8] = {w0.x, w0.y, w0.z, w0.w, w1v.x, w1v.y, w1v.z, w1v.w};
#pragma unroll
    for (int i = 0; i < 4; i++)
#pragma unroll
      for (int j = 0; j < 8; j++) acc2[i][j] = fmaf(a4[i], wv[j], acc2[i][j]);
  }

#pragma unroll
  for (int i = 0; i < 4; i++) {
    const int g = n0 + tm * 4 + i;
    if (g < n) {
      if (OUTBF) {
        // 8 outs -> one uint4 (8 bf16); row = 64 bf16 = 8 uint4
        uint4 u;
        u.x = packbf(acc2[i][0], acc2[i][1]);
        u.y = packbf(acc2[i][2], acc2[i][3]);
        u.z = packbf(acc2[i][4], acc2[i][5]);
        u.w = packbf(acc2[i][6], acc2[i][7]);
        ((uint4*)out)[(size_t)g * 8 + tn] = u;
      } else {
        ((float4*)out)[(size_t)g * 16 + tn * 2] =
            make_float4(acc2[i][0], acc2[i][1], acc2[i][2], acc2[i][3]);
        ((float4*)out)[(size_t)g * 16 + tn * 2 + 1] =
            make_float4(acc2[i][4], acc2[i][5], acc2[i][6], acc2[i][7]);
      }
    }
  }
}

// Classifier: out = relu(A@cw1 + cb1)@cw2 + cb2,  A:[n x 64] f32, out:[n x 16]
__global__ __launch_bounds__(256) void cls_tiled_kernel(
    const float* __restrict__ A, const float* __restrict__ w1,
    const float* __restrict__ b1, const float* __restrict__ w2,
    const float* __restrict__ b2, float* __restrict__ out, int n) {
  __shared__ float U[64 * 128];
  __shared__ float W1s[64 * 64];
  __shared__ float W2s[64 * 16];
  const int tid = threadIdx.x;
  const int n0 = blockIdx.x * 128;

  for (int i = tid; i < 1024; i += 256)
    ((float4*)W1s)[i] = ((const float4*)w1)[i];
  for (int i = tid; i < 256; i += 256)
    ((float4*)W2s)[i] = ((const float4*)w2)[i];

  for (int idx = tid; idx < 128 * 16; idx += 256) {
    const int node = idx >> 4;
    const int q = idx & 15;
    const int g = n0 + node;
    float4 v = make_float4(0.f, 0.f, 0.f, 0.f);
    if (g < n) v = ((const float4*)A)[(size_t)g * 16 + q];
    U[(q * 4 + 0) * 128 + node] = v.x;
    U[(q * 4 + 1) * 128 + node] = v.y;
    U[(q * 4 + 2) * 128 + node] = v.z;
    U[(q * 4 + 3) * 128 + node] = v.w;
  }
  __syncthreads();

  const int tm = tid & 31, tn = tid >> 5;

  float acc[4][8];
  {
    const float4 ba = *(const float4*)(b1 + tn * 8);
    const float4 bb = *(const float4*)(b1 + tn * 8 + 4);
#pragma unroll
    for (int i = 0; i < 4; i++) {
      acc[i][0] = ba.x; acc[i][1] = ba.y; acc[i][2] = ba.z; acc[i][3] = ba.w;
      acc[i][4] = bb.x; acc[i][5] = bb.y; acc[i][6] = bb.z; acc[i][7] = bb.w;
    }
  }
#pragma unroll 8
  for (int k = 0; k < 64; k++) {
    const float4 av = *(const float4*)&U[k * 128 + tm * 4];
    const float4 w0 = *(const float4*)&W1s[k * 64 + tn * 8];
    const float4 w1v = *(const float4*)&W1s[k * 64 + tn * 8 + 4];
    const float a4[4] = {av.x, av.y, av.z, av.w};
    const float wv[8] = {w0.x, w0.y, w0.z, w0.w, w1v.x, w1v.y, w1v.z, w1v.w};
#pragma unroll
    for (int i = 0; i < 4; i++)
#pragma unroll
      for (int j = 0; j < 8; j++) acc[i][j] = fmaf(a4[i], wv[j], acc[i][j]);
  }
#pragma unroll
  for (int i = 0; i < 4; i++)
#pragma unroll
    for (int j = 0; j < 8; j++) acc[i][j] = fmaxf(acc[i][j], 0.f);

  __syncthreads();
#pragma unroll
  for (int j = 0; j < 8; j++)
#pragma unroll
    for (int i = 0; i < 4; i++)
      U[(tn * 8 + j) * 128 + tm * 4 + i] = acc[i][j];
  __syncthreads();

  float acc2[4][2];
  {
    const float b0 = b2[tn * 2], b1v = b2[tn * 2 + 1];
#pragma unroll
    for (int i = 0; i < 4; i++) { acc2[i][0] = b0; acc2[i][1] = b1v; }
  }
#pragma unroll 8
  for (int k = 0; k < 64; k++) {
    const float4 av = *(const float4*)&U[k * 128 + tm * 4];
    const float wa = W2s[k * 16 + tn * 2];
    const float wb = W2s[k * 16 + tn * 2 + 1];
    const float a4[4] = {av.x, av.y, av.z, av.w};
#pragma unroll
    for (int i = 0; i < 4; i++) {
      acc2[i][0] = fmaf(a4[i], wa, acc2[i][0]);
      acc2[i][1] = fmaf(a4[i], wb, acc2[i][1]);
    }
  }
#pragma unroll
  for (int i = 0; i < 4; i++) {
    const int g = n0 + tm * 4 + i;
    if (g < n)
      ((float2*)out)[(size_t)g * 8 + tn] = make_float2(acc2[i][0], acc2[i][1]);
  }
}

extern "C" void kernel_launch(void* const* d_in, const int* in_sizes, int n_in,
                              void* d_out, int out_size, void* d_ws,
                              size_t ws_size, hipStream_t stream) {
  const float* x = (const float*)d_in[0];
  const int* ei = (const int*)d_in[1];
  const float* w1_0 = (const float*)d_in[2];
  const float* b1_0 = (const float*)d_in[3];
  const float* w2_0 = (const float*)d_in[4];
  const float* b2_0 = (const float*)d_in[5];
  const float* w1_1 = (const float*)d_in[6];
  const float* b1_1 = (const float*)d_in[7];
  const float* w2_1 = (const float*)d_in[8];
  const float* b2_1 = (const float*)d_in[9];
  const float* cw1 = (const float*)d_in[10];
  const float* cb1 = (const float*)d_in[11];
  const float* cw2 = (const float*)d_in[12];
  const float* cb2 = (const float*)d_in[13];

  const int n = in_sizes[0] / 32;  // nodes (< 2^17 for packing)
  const int ne = in_sizes[1] / 2;  // edges
  const int* src = ei;
  const int* dst = ei + ne;
  const int nb = (n + NPB - 1) / NPB;

  // Workspace layout
  float* aggr = (float*)d_ws;                       // n*64 f32 (agg union)
  float* h1 = aggr + (size_t)n * 64;                // n*64 f32
  uint2* xbf = (uint2*)(h1 + (size_t)n * 64);       // n*32 bf16 = n*8 uint2
  uint2* h0bf = xbf + (size_t)n * 8;                // n*64 bf16 = n*16 uint2
  int* sorted = (int*)(h0bf + (size_t)n * 16);      // ne
  int* csr = sorted + ne;                           // ne
  int* off = csr + ne;                              // n+1
  int* bcnt = off + n + 1;                          // nb
  int* boff = bcnt + nb;                            // nb+1
  int* bcur = boff + nb + 1;                        // nb

  // --- CSR build ---
  hipMemsetAsync(bcnt, 0, (size_t)nb * sizeof(int), stream);
  bucket_hist_kernel<<<220, 256, 0, stream>>>(dst, bcnt, ne, nb);
  bucket_scan_kernel<<<1, 512, 0, stream>>>(bcnt, boff, bcur, nb, ne);
  partition_kernel<<<(ne + CHUNK - 1) / CHUNK, 256, 0, stream>>>(
      src, dst, bcur, sorted, ne, nb);
  fill_bucket_kernel<<<nb, 256, 0, stream>>>(sorted, boff, off, csr, n, ne);

  // x -> bf16
  {
    const int n4 = n * 8;  // float4s in x
    f32_to_bf16_kernel<<<(n4 + 255) / 256, 256, 0, stream>>>(
        (const float4*)x, xbf, n4);
  }

  const int ntile = (n + 127) / 128;

  // --- Layer 0 ---
  gather_bf16_kernel<8><<<((size_t)n * 8 + 255) / 256, 256, 0, stream>>>(
      xbf, off, csr, aggr, n);
  mlp_pair_kernel<32, true><<<ntile, 256, 0, stream>>>(aggr, w1_0, b1_0, w2_0,
                                                       b2_0, h0bf, n);

  // --- Layer 1 ---
  gather_bf16_kernel<16><<<((size_t)n * 16 + 255) / 256, 256, 0, stream>>>(
      h0bf, off, csr, aggr, n);
  mlp_pair_kernel<64, false><<<ntile, 256, 0, stream>>>(aggr, w1_1, b1_1,
                                                        w2_1, b2_1, h1, n);

  // --- Classifier ---
  cls_tiled_kernel<<<ntile, 256, 0, stream>>>(h1, cw1, cb1, cw2, cb2,
                                              (float*)d_out, n);
}